// Round 1
// baseline (5994.067 us; speedup 1.0000x reference)
//
#include <hip/hip_runtime.h>
#include <math.h>

namespace {

constexpr int B = 2, S = 2048, D = 2048, H = 16, DHd = 128, A_DFF = 256;
constexpr int NRES = 8, NDENSE = 2;
constexpr float EPSV = 1e-6f;
constexpr float NEG_SLOPE = 0.2f;
constexpr float SCALE = 0.08838834764831843f; // 1/sqrt(128)

constexpr int TS = 64, KT = 16;

// ---------------------------------------------------------------------------
// Generic batched tiled GEMM.
// MODE 0: C = A[M,K] @ B[K,N]         (lda=K-ish row stride, ldb=N-ish)
// MODE 1: C = A[M,K] @ B[N,K]^T
// MODE 2: C = A[K,M]^T @ B[K,N]       (A stored K-major, lda = row stride)
// ACT 0: none, 1: SiLU.   C = scale*acc + bias[n]  (bias nullable)
// ldc == N. grid = (M/64, N/64, batch)
// ---------------------------------------------------------------------------
template<int MODE, int ACT>
__global__ __launch_bounds__(256) void gemm64(
    const float* __restrict__ A, const float* __restrict__ Bm,
    const float* __restrict__ bias, float* __restrict__ C,
    int M, int N, int K, int lda, int ldb,
    long sA, long sB, long sC, long sBias, float scale)
{
  A  += (long)blockIdx.z * sA;
  Bm += (long)blockIdx.z * sB;
  C  += (long)blockIdx.z * sC;
  if (bias) bias += (long)blockIdx.z * sBias;

  __shared__ float As[KT][TS + 4];
  __shared__ float Bs[KT][TS + 4];

  const int t = threadIdx.x;
  const int m0 = blockIdx.x * TS, n0 = blockIdx.y * TS;
  const int tm = (t & 15) * 4;      // 4 rows (m) per thread
  const int tn = (t >> 4) * 4;      // 4 cols (n) per thread

  float acc[4][4] = {};

  for (int k0 = 0; k0 < K; k0 += KT) {
    // ---- stage A tile: As[kk][mm] = A(m0+mm, k0+kk)
    if (MODE == 2) {
      const int kk = t >> 6, mm = t & 63;
#pragma unroll
      for (int p = 0; p < 4; ++p)
        As[kk + p * 4][mm] = A[(long)(k0 + kk + p * 4) * lda + m0 + mm];
    } else {
      const int kk = t & 15, mm = t >> 4;
#pragma unroll
      for (int p = 0; p < 4; ++p)
        As[kk][mm + p * 16] = A[(long)(m0 + mm + p * 16) * lda + k0 + kk];
    }
    // ---- stage B tile: Bs[kk][nn] = B(k0+kk, n0+nn)
    if (MODE == 1) {
      const int kk = t & 15, nn = t >> 4;
#pragma unroll
      for (int p = 0; p < 4; ++p)
        Bs[kk][nn + p * 16] = Bm[(long)(n0 + nn + p * 16) * ldb + k0 + kk];
    } else {
      const int kk = t >> 6, nn = t & 63;
#pragma unroll
      for (int p = 0; p < 4; ++p)
        Bs[kk + p * 4][nn] = Bm[(long)(k0 + kk + p * 4) * ldb + n0 + nn];
    }
    __syncthreads();

#pragma unroll
    for (int kk = 0; kk < KT; ++kk) {
      float4 av = *(const float4*)&As[kk][tm];
      float4 bv = *(const float4*)&Bs[kk][tn];
      float a[4] = {av.x, av.y, av.z, av.w};
      float b[4] = {bv.x, bv.y, bv.z, bv.w};
#pragma unroll
      for (int i = 0; i < 4; ++i)
#pragma unroll
        for (int j = 0; j < 4; ++j)
          acc[i][j] += a[i] * b[j];
    }
    __syncthreads();
  }

#pragma unroll
  for (int i = 0; i < 4; ++i) {
    const int m = m0 + tm + i;
#pragma unroll
    for (int j = 0; j < 4; ++j) {
      const int n = n0 + tn + j;
      float c = acc[i][j] * scale;
      if (bias) c += bias[n];
      if (ACT == 1) c = c / (1.f + __expf(-c));
      C[(long)m * N + n] = c;
    }
  }
}

// ---------------------------------------------------------------------------
// LayerNorm over rows of 128, one wave per row. res nullable (added first).
// In-place safe (out may equal in).
// ---------------------------------------------------------------------------
__global__ __launch_bounds__(64) void ln_row(
    const float* __restrict__ in, const float* __restrict__ res,
    const float* __restrict__ g, const float* __restrict__ b,
    float* __restrict__ out)
{
  const long r = blockIdx.x;
  const int t = threadIdx.x;
  float v0 = in[r * 128 + t], v1 = in[r * 128 + t + 64];
  if (res) { v0 += res[r * 128 + t]; v1 += res[r * 128 + t + 64]; }
  float s = v0 + v1;
#pragma unroll
  for (int o = 32; o > 0; o >>= 1) s += __shfl_down(s, o);
  const float mu = __shfl(s, 0) * (1.f / 128.f);
  const float d0 = v0 - mu, d1 = v1 - mu;
  float vs = d0 * d0 + d1 * d1;
#pragma unroll
  for (int o = 32; o > 0; o >>= 1) vs += __shfl_down(vs, o);
  const float rstd = rsqrtf(__shfl(vs, 0) * (1.f / 128.f) + EPSV);
  out[r * 128 + t]      = d0 * rstd * g[t] + b[t];
  out[r * 128 + t + 64] = d1 * rstd * g[t + 64] + b[t + 64];
}

// [B,S,H,DH] -> [B,H,S,DH] with interleaved-pair RoPE. One thread per pair.
__global__ __launch_bounds__(256) void rope_tr(const float* __restrict__ in,
                                               float* __restrict__ out)
{
  const long idx = (long)blockIdx.x * 256 + threadIdx.x;  // B*S*H*64
  const int p = idx & 63;
  const int h = (idx >> 6) & (H - 1);
  const int s = (idx >> 10) & (S - 1);
  const int b = (int)(idx >> 21);
  const float theta = powf(10000.f, -(float)p * (1.f / 64.f));
  float sn, cs;
  sincosf((float)s * theta, &sn, &cs);
  const long src = (((long)(b * S + s) * H + h) << 7) + 2 * p;
  const float x1 = in[src], x2 = in[src + 1];
  const long dst = (((long)(b * H + h) * S + s) << 7) + 2 * p;
  out[dst]     = x1 * cs - x2 * sn;
  out[dst + 1] = x2 * cs + x1 * sn;
}

// [B,S,H,DH] -> [B,H,S,DH]
__global__ __launch_bounds__(256) void tr_heads(const float* __restrict__ in,
                                                float* __restrict__ out)
{
  const long idx = (long)blockIdx.x * 256 + threadIdx.x;  // B*H*S*DH (out-linear)
  const int d = idx & 127;
  const int s = (idx >> 7) & (S - 1);
  const int h = (idx >> 18) & (H - 1);
  const int b = (int)(idx >> 22);
  out[idx] = in[(((long)(b * S + s) * H + h) << 7) + d];
}

// [B,H,S,DH] -> [B,S,H,DH]
__global__ __launch_bounds__(256) void untr_heads(const float* __restrict__ in,
                                                  float* __restrict__ out)
{
  const long idx = (long)blockIdx.x * 256 + threadIdx.x;  // B*S*H*DH (out-linear)
  const int d = idx & 127;
  const int h = (idx >> 7) & (H - 1);
  const int s = (idx >> 11) & (S - 1);
  const int b = (int)(idx >> 22);
  out[idx] = in[(((long)(b * H + h) * S + s) << 7) + d];
}

__global__ __launch_bounds__(256) void ew_mul(float* __restrict__ x,
                                              const float* __restrict__ y)
{
  const long i = (long)blockIdx.x * 256 + threadIdx.x;
  x[i] *= y[i];
}

// leaky_relu then G = sign(y)*pow(|y|+eps, pw[h]); in-place on [B,H,128,128]
__global__ __launch_bounds__(256) void plga_g(float* __restrict__ a,
                                              const float* __restrict__ pw)
{
  const long idx = (long)blockIdx.x * 256 + threadIdx.x;
  const int h = (idx >> 14) & (H - 1);
  float x = a[idx];
  x = x > 0.f ? x : NEG_SLOPE * x;
  const float gq = powf(fabsf(x) + EPSV, pw[h]);
  a[idx] = x > 0.f ? gq : (x < 0.f ? -gq : 0.f);
}

// causal softmax on score chunk [32][128][2048]; row r -> (bh, sl); global
// q index = chunk0 + sl; entries t > sglob get probability 0.
__global__ __launch_bounds__(256) void softmax_causal(float* __restrict__ sc,
                                                      int chunk0)
{
  const int r = blockIdx.x;               // 0 .. 32*128
  const int sl = r & 127;
  const int sglob = chunk0 + sl;
  float* row = sc + (long)r * S;
  const int t = threadIdx.x;
  const int valid = sglob + 1;
  __shared__ float red[256];

  float mx = -1e30f;
  for (int i = t; i < valid; i += 256) mx = fmaxf(mx, row[i]);
  red[t] = mx; __syncthreads();
  for (int o = 128; o > 0; o >>= 1) { if (t < o) red[t] = fmaxf(red[t], red[t + o]); __syncthreads(); }
  mx = red[0]; __syncthreads();

  float sum = 0.f;
  for (int i = t; i < valid; i += 256) {
    const float e = __expf(row[i] - mx);
    row[i] = e;
    sum += e;
  }
  red[t] = sum; __syncthreads();
  for (int o = 128; o > 0; o >>= 1) { if (t < o) red[t] += red[t + o]; __syncthreads(); }
  const float inv = 1.f / red[0];

  for (int i = t; i < valid; i += 256) row[i] *= inv;
  for (int i = valid + t; i < S; i += 256) row[i] = 0.f;
}

}  // namespace

extern "C" void kernel_launch(void* const* d_in, const int* in_sizes, int n_in,
                              void* d_out, int out_size, void* d_ws, size_t ws_size,
                              hipStream_t stream)
{
  const float* q_in    = (const float*)d_in[0];
  const float* k_in    = (const float*)d_in[1];
  const float* v_in    = (const float*)d_in[2];
  // d_in[3] = mask (pure causal; implemented directly)
  const float* wq_w    = (const float*)d_in[4];
  const float* wq_b    = (const float*)d_in[5];
  const float* wk_w    = (const float*)d_in[6];
  const float* wk_b    = (const float*)d_in[7];
  const float* wv_w    = (const float*)d_in[8];
  const float* wv_b    = (const float*)d_in[9];
  const float* dense_w = (const float*)d_in[10];
  const float* dense_b = (const float*)d_in[11];
  const float* ln1_g   = (const float*)d_in[12];
  const float* ln1_b   = (const float*)d_in[13];
  const float* res_w1  = (const float*)d_in[14];
  const float* res_b1  = (const float*)d_in[15];
  const float* res_w2  = (const float*)d_in[16];
  const float* res_b2  = (const float*)d_in[17];
  const float* res_w3  = (const float*)d_in[18];
  const float* res_b3  = (const float*)d_in[19];
  const float* res_lng = (const float*)d_in[20];
  const float* res_lnb = (const float*)d_in[21];
  const float* plga_W  = (const float*)d_in[22];
  const float* plga_b  = (const float*)d_in[23];
  const float* plga_pw = (const float*)d_in[24];
  float* out = (float*)d_out;

  float* ws = (float*)d_ws;
  const long NBS = (long)B * S * D;            // 8388608
  const long NA  = (long)B * H * DHd * DHd;    // 524288
  const long NX  = (long)B * H * DHd * A_DFF;  // 1048576
  float* qp   = ws;            // q projection, later reused as qG
  float* kp   = qp + NBS;      // k projection, later reused as Hn ([B,H,S,DH])
  float* vp   = kp + NBS;      // v projection, later reused as score chunks
  float* qh   = vp + NBS;      // q heads [B,H,S,DH]; later reused for Hn^T
  float* kh   = qh + NBS;
  float* vh   = kh + NBS;
  float* Abuf = vh + NBS;
  float* Ain  = Abuf + NA;
  float* X1   = Ain + NA;
  float* X2   = X1 + NX;
  float* Gb   = X2 + NX;

  // ---- QKV projections: [B*S, D] @ W^T + b
  gemm64<1, 0><<<dim3(64, 32, 1), 256, 0, stream>>>(q_in, wq_w, wq_b, qp,
      B * S, D, D, D, D, 0, 0, 0, 0, 1.f);
  gemm64<1, 0><<<dim3(64, 32, 1), 256, 0, stream>>>(k_in, wk_w, wk_b, kp,
      B * S, D, D, D, D, 0, 0, 0, 0, 1.f);
  gemm64<1, 0><<<dim3(64, 32, 1), 256, 0, stream>>>(v_in, wv_w, wv_b, vp,
      B * S, D, D, D, D, 0, 0, 0, 0, 1.f);

  // ---- RoPE + transpose to [B,H,S,DH]
  rope_tr<<<16384, 256, 0, stream>>>(qp, qh);
  rope_tr<<<16384, 256, 0, stream>>>(kp, kh);
  tr_heads<<<32768, 256, 0, stream>>>(vp, vh);

  // ---- metric A = q^T q per (b,h): [128,128], K = S
  gemm64<2, 0><<<dim3(2, 2, 32), 256, 0, stream>>>(qh, qh, nullptr, Abuf,
      DHd, DHd, S, DHd, DHd, (long)S * DHd, (long)S * DHd, NA / (B * H) * 1, 0, 1.f);
  ln_row<<<B * H * DHd, 64, 0, stream>>>(Abuf, nullptr, ln1_g, ln1_b, Abuf);

  // ---- residual SwiGLU stack
  for (int l = 0; l < NRES; ++l) {
    hipMemcpyAsync(Ain, Abuf, sizeof(float) * NA, hipMemcpyDeviceToDevice, stream);
    for (int n = 0; n < NDENSE; ++n) {
      const long wo = (long)(l * NDENSE + n);
      const float* w1 = res_w1 + wo * A_DFF * DHd;
      const float* b1 = res_b1 + wo * A_DFF;
      const float* w2 = res_w2 + wo * A_DFF * DHd;
      const float* b2 = res_b2 + wo * A_DFF;
      const float* w3 = res_w3 + wo * DHd * A_DFF;
      const float* b3 = res_b3 + wo * DHd;
      gemm64<1, 1><<<dim3(2, 4, 32), 256, 0, stream>>>(Abuf, w1, b1, X1,
          DHd, A_DFF, DHd, DHd, DHd, (long)DHd * DHd, 0, (long)DHd * A_DFF, 0, 1.f);
      gemm64<1, 0><<<dim3(2, 4, 32), 256, 0, stream>>>(Abuf, w2, b2, X2,
          DHd, A_DFF, DHd, DHd, DHd, (long)DHd * DHd, 0, (long)DHd * A_DFF, 0, 1.f);
      ew_mul<<<(int)(NX / 256), 256, 0, stream>>>(X1, X2);
      gemm64<1, 0><<<dim3(2, 2, 32), 256, 0, stream>>>(X1, w3, b3, Abuf,
          DHd, DHd, A_DFF, A_DFF, A_DFF, (long)DHd * A_DFF, 0, (long)DHd * DHd, 0, 1.f);
    }
    ln_row<<<B * H * DHd, 64, 0, stream>>>(Abuf, Ain, res_lng + l * DHd,
                                           res_lnb + l * DHd, Abuf);
  }

  // ---- plga: A_LM = W[h] @ A[b,h] + b[h]  (NN, batch over h; loop over b)
  for (int b2 = 0; b2 < B; ++b2)
    gemm64<0, 0><<<dim3(2, 2, 16), 256, 0, stream>>>(plga_W,
        Abuf + (long)b2 * H * DHd * DHd, plga_b, Gb + (long)b2 * H * DHd * DHd,
        DHd, DHd, DHd, DHd, DHd,
        (long)DHd * DHd, (long)DHd * DHd, (long)DHd * DHd, DHd, 1.f);
  plga_g<<<(int)(NA / 256), 256, 0, stream>>>(Gb, plga_pw);

  // ---- qg = q @ G per (b,h): [S,128]
  gemm64<0, 0><<<dim3(32, 2, 32), 256, 0, stream>>>(qh, Gb, nullptr, qp,
      S, DHd, DHd, DHd, DHd, (long)S * DHd, (long)DHd * DHd, (long)S * DHd, 0, 1.f);

  // ---- attention in chunks of 128 q-rows; scores chunk lives in vp
  for (int c = 0; c < S / 128; ++c) {
    gemm64<1, 0><<<dim3(2, 32, 32), 256, 0, stream>>>(qp + (long)c * 128 * DHd,
        kh, nullptr, vp, 128, S, DHd, DHd, DHd,
        (long)S * DHd, (long)S * DHd, (long)128 * S, 0, SCALE);
    softmax_causal<<<32 * 128, 256, 0, stream>>>(vp, c * 128);
    gemm64<0, 0><<<dim3(2, 2, 32), 256, 0, stream>>>(vp, vh, nullptr,
        kp + (long)c * 128 * DHd, 128, DHd, S, S, DHd,
        (long)128 * S, (long)S * DHd, (long)S * DHd, 0, 1.f);
  }

  // ---- back to [B,S,D] and final dense
  untr_heads<<<32768, 256, 0, stream>>>(kp, qh);
  gemm64<1, 0><<<dim3(64, 32, 1), 256, 0, stream>>>(qh, dense_w, dense_b, out,
      B * S, D, D, D, D, 0, 0, 0, 0, 1.f);
}

// Round 2
// 2390.496 us; speedup vs baseline: 2.5075x; 2.5075x over previous
//
#include <hip/hip_runtime.h>
#include <hip/hip_bf16.h>
#include <math.h>

namespace {

constexpr int B = 2, S = 2048, D = 2048, H = 16, DHd = 128, A_DFF = 256;
constexpr int NRES = 8, NDENSE = 2;
constexpr float EPSV = 1e-6f;
constexpr float NEG_SLOPE = 0.2f;
constexpr float SCALE = 0.08838834764831843f; // 1/sqrt(128)

constexpr int TS = 64, KT = 16;

using bf16 = __hip_bfloat16;
using short8 = __attribute__((ext_vector_type(8))) short;
using f32x4  = __attribute__((ext_vector_type(4))) float;

typedef const __attribute__((address_space(1))) unsigned int* gas_ptr;
typedef __attribute__((address_space(3))) unsigned int* las_ptr;

__device__ __forceinline__ void glds16(const void* g, void* l) {
  __builtin_amdgcn_global_load_lds((gas_ptr)g, (las_ptr)l, 16, 0, 0);
}

// ---------------------------------------------------------------------------
// bf16 MFMA GEMM: C[M,N] = scale * (A[M,K] @ Bt[N,K]^T) + bias
// 128x128 tile, BK=32, 256 threads (4 waves, each 64x64), m97 structure.
// grid = (M/128, n_tiles, batch). ldc row stride of C. All dims %128==0 (K%32).
// ---------------------------------------------------------------------------
template<bool OUT_BF16, bool BIAS>
__global__ __launch_bounds__(256) void gemm_bt_mfma(
    const bf16* __restrict__ A, const bf16* __restrict__ Bt,
    const float* __restrict__ bias, void* __restrict__ Cv,
    int K, int lda, int ldb, int ldc,
    long sA, long sB, long sC, float scale)
{
  A  += (long)blockIdx.z * sA;
  Bt += (long)blockIdx.z * sB;

  __shared__ short As[128 * 32] __attribute__((aligned(16)));
  __shared__ short Bs[128 * 32] __attribute__((aligned(16)));

  const int t = threadIdx.x;
  const int wv = t >> 6, l = t & 63;
  const int m0 = blockIdx.x * 128, n0 = blockIdx.y * 128;

  // staging coords: thread t covers 8 bf16 at row (t>>2), col (t&3)*8
  const int sr = t >> 2, sc = (t & 3) * 8;
  short* ldsA0 = As + wv * 512;          // wave-uniform bases (lane adds l*16B)
  short* ldsA1 = As + 2048 + wv * 512;
  short* ldsB0 = Bs + wv * 512;
  short* ldsB1 = Bs + 2048 + wv * 512;

  // wave -> 64x64 quadrant
  const int wr = wv >> 1, wc = wv & 1;
  const int lr = l & 15, lk = (l >> 4) * 8;

  f32x4 acc[4][4] = {};

  for (int k0 = 0; k0 < K; k0 += 32) {
    __syncthreads();
    glds16(A  + (long)(m0 + sr)      * lda + k0 + sc, ldsA0);
    glds16(A  + (long)(m0 + 64 + sr) * lda + k0 + sc, ldsA1);
    glds16(Bt + (long)(n0 + sr)      * ldb + k0 + sc, ldsB0);
    glds16(Bt + (long)(n0 + 64 + sr) * ldb + k0 + sc, ldsB1);
    __syncthreads();

    short8 af[4], bf[4];
#pragma unroll
    for (int m = 0; m < 4; ++m)
      af[m] = *(const short8*)&As[(wr * 64 + m * 16 + lr) * 32 + lk];
#pragma unroll
    for (int n = 0; n < 4; ++n)
      bf[n] = *(const short8*)&Bs[(wc * 64 + n * 16 + lr) * 32 + lk];
#pragma unroll
    for (int m = 0; m < 4; ++m)
#pragma unroll
      for (int n = 0; n < 4; ++n)
        acc[m][n] = __builtin_amdgcn_mfma_f32_16x16x32_bf16(af[m], bf[n], acc[m][n], 0, 0, 0);
  }

  const int rb = m0 + wr * 64 + (l >> 4) * 4;
  const int cb = n0 + wc * 64 + (l & 15);
#pragma unroll
  for (int m = 0; m < 4; ++m)
#pragma unroll
    for (int n = 0; n < 4; ++n) {
      const int col = cb + n * 16;
      float bv = BIAS ? bias[col] : 0.f;
#pragma unroll
      for (int r = 0; r < 4; ++r) {
        const long off = (long)(rb + m * 16 + r) * ldc + col + blockIdx.z * sC;
        const float c = acc[m][n][r] * scale + bv;
        if (OUT_BF16) ((bf16*)Cv)[off] = __float2bfloat16(c);
        else          ((float*)Cv)[off] = c;
      }
    }
}

// ---------------------------------------------------------------------------
// fp32 fallback GEMM (small matrices: metric stack). Same semantics as before.
// MODE 0: C=A@B, 1: C=A@B^T, 2: C=A^T@B. ACT 1: SiLU.
// ---------------------------------------------------------------------------
template<int MODE, int ACT>
__global__ __launch_bounds__(256) void gemm64(
    const float* __restrict__ A, const float* __restrict__ Bm,
    const float* __restrict__ bias, float* __restrict__ C,
    int M, int N, int K, int lda, int ldb,
    long sA, long sB, long sC, long sBias, float scale)
{
  A  += (long)blockIdx.z * sA;
  Bm += (long)blockIdx.z * sB;
  C  += (long)blockIdx.z * sC;
  if (bias) bias += (long)blockIdx.z * sBias;

  __shared__ float As[KT][TS + 4];
  __shared__ float Bs[KT][TS + 4];

  const int t = threadIdx.x;
  const int m0 = blockIdx.x * TS, n0 = blockIdx.y * TS;
  const int tm = (t & 15) * 4;
  const int tn = (t >> 4) * 4;

  float acc[4][4] = {};

  for (int k0 = 0; k0 < K; k0 += KT) {
    if (MODE == 2) {
      const int kk = t >> 6, mm = t & 63;
#pragma unroll
      for (int p = 0; p < 4; ++p)
        As[kk + p * 4][mm] = A[(long)(k0 + kk + p * 4) * lda + m0 + mm];
    } else {
      const int kk = t & 15, mm = t >> 4;
#pragma unroll
      for (int p = 0; p < 4; ++p)
        As[kk][mm + p * 16] = A[(long)(m0 + mm + p * 16) * lda + k0 + kk];
    }
    if (MODE == 1) {
      const int kk = t & 15, nn = t >> 4;
#pragma unroll
      for (int p = 0; p < 4; ++p)
        Bs[kk][nn + p * 16] = Bm[(long)(n0 + nn + p * 16) * ldb + k0 + kk];
    } else {
      const int kk = t >> 6, nn = t & 63;
#pragma unroll
      for (int p = 0; p < 4; ++p)
        Bs[kk + p * 4][nn] = Bm[(long)(k0 + kk + p * 4) * ldb + n0 + nn];
    }
    __syncthreads();

#pragma unroll
    for (int kk = 0; kk < KT; ++kk) {
      float4 av = *(const float4*)&As[kk][tm];
      float4 bv = *(const float4*)&Bs[kk][tn];
      float a[4] = {av.x, av.y, av.z, av.w};
      float b[4] = {bv.x, bv.y, bv.z, bv.w};
#pragma unroll
      for (int i = 0; i < 4; ++i)
#pragma unroll
        for (int j = 0; j < 4; ++j)
          acc[i][j] += a[i] * b[j];
    }
    __syncthreads();
  }

#pragma unroll
  for (int i = 0; i < 4; ++i) {
    const int m = m0 + tm + i;
#pragma unroll
    for (int j = 0; j < 4; ++j) {
      const int n = n0 + tn + j;
      float c = acc[i][j] * scale;
      if (bias) c += bias[n];
      if (ACT == 1) c = c / (1.f + __expf(-c));
      C[(long)m * N + n] = c;
    }
  }
}

// f32 -> bf16 convert, 4 elems/thread
__global__ __launch_bounds__(256) void f2b(const float* __restrict__ in,
                                           bf16* __restrict__ out)
{
  const long i = (long)blockIdx.x * 256 + threadIdx.x;
  const float4 v = ((const float4*)in)[i];
  bf16* o = out + i * 4;
  o[0] = __float2bfloat16(v.x); o[1] = __float2bfloat16(v.y);
  o[2] = __float2bfloat16(v.z); o[3] = __float2bfloat16(v.w);
}

// LayerNorm rows of 128, one wave per row (in-place safe); res nullable.
__global__ __launch_bounds__(64) void ln_row(
    const float* __restrict__ in, const float* __restrict__ res,
    const float* __restrict__ g, const float* __restrict__ b,
    float* __restrict__ out)
{
  const long r = blockIdx.x;
  const int t = threadIdx.x;
  float v0 = in[r * 128 + t], v1 = in[r * 128 + t + 64];
  if (res) { v0 += res[r * 128 + t]; v1 += res[r * 128 + t + 64]; }
  float s = v0 + v1;
#pragma unroll
  for (int o = 32; o > 0; o >>= 1) s += __shfl_down(s, o);
  const float mu = __shfl(s, 0) * (1.f / 128.f);
  const float d0 = v0 - mu, d1 = v1 - mu;
  float vs = d0 * d0 + d1 * d1;
#pragma unroll
  for (int o = 32; o > 0; o >>= 1) vs += __shfl_down(vs, o);
  const float rstd = rsqrtf(__shfl(vs, 0) * (1.f / 128.f) + EPSV);
  out[r * 128 + t]      = d0 * rstd * g[t] + b[t];
  out[r * 128 + t + 64] = d1 * rstd * g[t + 64] + b[t + 64];
}

// [B,S,H,DH] f32 -> [B,H,S,DH] with RoPE; writes optional f32 + bf16.
__global__ __launch_bounds__(256) void rope_tr2(const float* __restrict__ in,
                                                float* __restrict__ outf,
                                                bf16* __restrict__ outb)
{
  const long idx = (long)blockIdx.x * 256 + threadIdx.x;  // B*S*H*64 pairs
  const int p = idx & 63;
  const int h = (idx >> 6) & (H - 1);
  const int s = (idx >> 10) & (S - 1);
  const int b = (int)(idx >> 21);
  const float theta = powf(10000.f, -(float)p * (1.f / 64.f));
  float sn, cs;
  sincosf((float)s * theta, &sn, &cs);
  const long src = (((long)(b * S + s) * H + h) << 7) + 2 * p;
  const float x1 = in[src], x2 = in[src + 1];
  const long dst = (((long)(b * H + h) * S + s) << 7) + 2 * p;
  const float o1 = x1 * cs - x2 * sn, o2 = x2 * cs + x1 * sn;
  if (outf) { outf[dst] = o1; outf[dst + 1] = o2; }
  outb[dst]     = __float2bfloat16(o1);
  outb[dst + 1] = __float2bfloat16(o2);
}

// [B,S,H,DH] f32 -> vT bf16 [B,H,DH,S]
__global__ __launch_bounds__(256) void tr_v_b(const float* __restrict__ in,
                                              bf16* __restrict__ out)
{
  const long idx = (long)blockIdx.x * 256 + threadIdx.x;  // out-linear
  const int s = idx & (S - 1);
  const int dh = (idx >> 11) & 127;
  const int h = (idx >> 18) & (H - 1);
  const int b = (int)(idx >> 22);
  out[idx] = __float2bfloat16(in[(((long)(b * S + s) * H + h) << 7) + dh]);
}

// Hnbh bf16 [B,H,S,DH] -> Hnb bf16 [B,S,H*DH]
__global__ __launch_bounds__(256) void untr_b(const bf16* __restrict__ in,
                                              bf16* __restrict__ out)
{
  const long idx = (long)blockIdx.x * 256 + threadIdx.x;  // out-linear
  const int d = idx & 127;
  const int h = (idx >> 7) & (H - 1);
  const int s = (idx >> 11) & (S - 1);
  const int b = (int)(idx >> 22);
  out[idx] = in[(((long)(b * H + h) * S + s) << 7) + d];
}

__global__ __launch_bounds__(256) void ew_mul(float* __restrict__ x,
                                              const float* __restrict__ y)
{
  const long i = (long)blockIdx.x * 256 + threadIdx.x;
  x[i] *= y[i];
}

// G = sign/pow(leaky_relu(A_LM)); reads Gb f32 [bh,d,f], writes transposed
// bf16 GTb [bh,f,d] for use as Bt operand of qG.
__global__ __launch_bounds__(256) void plga_g_t(const float* __restrict__ a,
                                                const float* __restrict__ pw,
                                                bf16* __restrict__ gt)
{
  const long idx = (long)blockIdx.x * 256 + threadIdx.x;
  const int f = idx & 127;
  const int dd = (idx >> 7) & 127;
  const int bh = (int)(idx >> 14);
  const int h = bh & (H - 1);
  float x = a[idx];
  x = x > 0.f ? x : NEG_SLOPE * x;
  const float gq = powf(fabsf(x) + EPSV, pw[h]);
  const float gv = x > 0.f ? gq : (x < 0.f ? -gq : 0.f);
  gt[((long)bh << 14) + f * 128 + dd] = __float2bfloat16(gv);
}

// causal softmax: read f32 scores chunk [32*128][S], write bf16 probs
// over [0, Kv) (zeros beyond the causal prefix).
__global__ __launch_bounds__(256) void softmax_causal_b(
    const float* __restrict__ sc, bf16* __restrict__ pb, int chunk0)
{
  const int r = blockIdx.x;               // 0 .. 32*128
  const int sl = r & 127;
  const int valid = chunk0 + sl + 1;
  const int Kv = chunk0 + 128;
  const float* row = sc + (long)r * S;
  bf16* prow = pb + (long)r * S;
  const int t = threadIdx.x;
  __shared__ float red[256];

  float mx = -1e30f;
  for (int i = t; i < valid; i += 256) mx = fmaxf(mx, row[i]);
  red[t] = mx; __syncthreads();
  for (int o = 128; o > 0; o >>= 1) { if (t < o) red[t] = fmaxf(red[t], red[t + o]); __syncthreads(); }
  mx = red[0]; __syncthreads();

  float sum = 0.f;
  for (int i = t; i < valid; i += 256) sum += __expf(row[i] - mx);
  red[t] = sum; __syncthreads();
  for (int o = 128; o > 0; o >>= 1) { if (t < o) red[t] += red[t + o]; __syncthreads(); }
  const float inv = 1.f / red[0];

  for (int i = t; i < valid; i += 256) prow[i] = __float2bfloat16(__expf(row[i] - mx) * inv);
  for (int i = valid + t; i < Kv; i += 256) prow[i] = __float2bfloat16(0.f);
}

}  // namespace

extern "C" void kernel_launch(void* const* d_in, const int* in_sizes, int n_in,
                              void* d_out, int out_size, void* d_ws, size_t ws_size,
                              hipStream_t stream)
{
  const float* q_in    = (const float*)d_in[0];
  const float* k_in    = (const float*)d_in[1];
  const float* v_in    = (const float*)d_in[2];
  const float* wq_w    = (const float*)d_in[4];
  const float* wq_b    = (const float*)d_in[5];
  const float* wk_w    = (const float*)d_in[6];
  const float* wk_b    = (const float*)d_in[7];
  const float* wv_w    = (const float*)d_in[8];
  const float* wv_b    = (const float*)d_in[9];
  const float* dense_w = (const float*)d_in[10];
  const float* dense_b = (const float*)d_in[11];
  const float* ln1_g   = (const float*)d_in[12];
  const float* ln1_b   = (const float*)d_in[13];
  const float* res_w1  = (const float*)d_in[14];
  const float* res_b1  = (const float*)d_in[15];
  const float* res_w2  = (const float*)d_in[16];
  const float* res_b2  = (const float*)d_in[17];
  const float* res_w3  = (const float*)d_in[18];
  const float* res_b3  = (const float*)d_in[19];
  const float* res_lng = (const float*)d_in[20];
  const float* res_lnb = (const float*)d_in[21];
  const float* plga_W  = (const float*)d_in[22];
  const float* plga_b  = (const float*)d_in[23];
  const float* plga_pw = (const float*)d_in[24];
  float* out = (float*)d_out;

  const long NBS = (long)B * S * D;            // 8388608
  const long NA  = (long)B * H * DHd * DHd;    // 524288
  const long NX  = (long)B * H * DHd * A_DFF;  // 1048576
  const long DDw = (long)D * D;                // 4194304

  float* ws = (float*)d_ws;
  // f32 slots
  float* qp = ws;               // q proj f32; later: probs bf16 (as ushort)
  float* kp = ws + NBS;         // k proj f32; later: Hnbh + Hnb bf16
  float* vp = ws + 2 * NBS;     // v proj f32; later: small f32 stack, then scores chunk
  float* qh = ws + 3 * NBS;     // rope'd q f32; later: GTb bf16
  // small f32 (inside vp slot, live only between tr_v_b and attention loop)
  float* Abuf = vp;
  float* Ain  = vp + NA;
  float* Gb   = vp + 2 * NA;
  float* X1   = vp + 3 * NA;
  float* X2   = vp + 3 * NA + NX;
  float* scoresf = vp;          // attention-phase alias
  // bf16 region
  bf16* bbase = (bf16*)(ws + 4 * NBS);
  bf16* qb  = bbase;            // q_in bf16; later qhb
  bf16* kb  = bbase + NBS;      // k_in bf16; later khb
  bf16* vb  = bbase + 2 * NBS;  // v_in bf16; later vT
  bf16* wqb = bbase + 3 * NBS;  // later qgb (spans wqb+wkb)
  bf16* wkb = wqb + DDw;
  bf16* wvb = wqb + 2 * DDw;    // later wdb
  bf16* qhb = qb;
  bf16* khb = kb;
  bf16* vT  = vb;
  bf16* qgb = wqb;
  bf16* wdb = wvb;
  bf16* GTb = (bf16*)qh;
  bf16* probsb = (bf16*)qp;
  bf16* Hnbh = (bf16*)kp;
  bf16* Hnb  = Hnbh + NBS;

  // ---- convert inputs + QKV weights to bf16
  f2b<<<(int)(NBS / 1024), 256, 0, stream>>>(q_in, qb);
  f2b<<<(int)(NBS / 1024), 256, 0, stream>>>(k_in, kb);
  f2b<<<(int)(NBS / 1024), 256, 0, stream>>>(v_in, vb);
  f2b<<<(int)(DDw / 1024), 256, 0, stream>>>(wq_w, wqb);
  f2b<<<(int)(DDw / 1024), 256, 0, stream>>>(wk_w, wkb);
  f2b<<<(int)(DDw / 1024), 256, 0, stream>>>(wv_w, wvb);

  // ---- QKV projections (bf16 MFMA): [4096,2048] = in @ W^T + b
  gemm_bt_mfma<false, true><<<dim3(32, 16, 1), 256, 0, stream>>>(
      qb, wqb, wq_b, qp, D, D, D, D, 0, 0, 0, 1.f);
  gemm_bt_mfma<false, true><<<dim3(32, 16, 1), 256, 0, stream>>>(
      kb, wkb, wk_b, kp, D, D, D, D, 0, 0, 0, 1.f);
  gemm_bt_mfma<false, true><<<dim3(32, 16, 1), 256, 0, stream>>>(
      vb, wvb, wv_b, vp, D, D, D, D, 0, 0, 0, 1.f);

  // dense weight -> bf16 (into wvb slot, now dead)
  f2b<<<(int)(DDw / 1024), 256, 0, stream>>>(dense_w, wdb);

  // ---- RoPE + head transpose
  rope_tr2<<<16384, 256, 0, stream>>>(qp, qh, qhb);
  rope_tr2<<<16384, 256, 0, stream>>>(kp, nullptr, khb);
  tr_v_b<<<32768, 256, 0, stream>>>(vp, vT);

  // ---- metric A = q^T q per (b,h)  (fp32)
  gemm64<2, 0><<<dim3(2, 2, 32), 256, 0, stream>>>(qh, qh, nullptr, Abuf,
      DHd, DHd, S, DHd, DHd, (long)S * DHd, (long)S * DHd, (long)DHd * DHd, 0, 1.f);
  ln_row<<<B * H * DHd, 64, 0, stream>>>(Abuf, nullptr, ln1_g, ln1_b, Abuf);

  // ---- residual SwiGLU stack (fp32)
  for (int l = 0; l < NRES; ++l) {
    hipMemcpyAsync(Ain, Abuf, sizeof(float) * NA, hipMemcpyDeviceToDevice, stream);
    for (int n = 0; n < NDENSE; ++n) {
      const long wo = (long)(l * NDENSE + n);
      const float* w1 = res_w1 + wo * A_DFF * DHd;
      const float* b1 = res_b1 + wo * A_DFF;
      const float* w2 = res_w2 + wo * A_DFF * DHd;
      const float* b2 = res_b2 + wo * A_DFF;
      const float* w3 = res_w3 + wo * DHd * A_DFF;
      const float* b3 = res_b3 + wo * DHd;
      gemm64<1, 1><<<dim3(2, 4, 32), 256, 0, stream>>>(Abuf, w1, b1, X1,
          DHd, A_DFF, DHd, DHd, DHd, (long)DHd * DHd, 0, (long)DHd * A_DFF, 0, 1.f);
      gemm64<1, 0><<<dim3(2, 4, 32), 256, 0, stream>>>(Abuf, w2, b2, X2,
          DHd, A_DFF, DHd, DHd, DHd, (long)DHd * DHd, 0, (long)DHd * A_DFF, 0, 1.f);
      ew_mul<<<(int)(NX / 256), 256, 0, stream>>>(X1, X2);
      gemm64<1, 0><<<dim3(2, 2, 32), 256, 0, stream>>>(X1, w3, b3, Abuf,
          DHd, DHd, A_DFF, A_DFF, A_DFF, (long)DHd * A_DFF, 0, (long)DHd * DHd, 0, 1.f);
    }
    ln_row<<<B * H * DHd, 64, 0, stream>>>(Abuf, Ain, res_lng + l * DHd,
                                           res_lnb + l * DHd, Abuf);
  }

  // ---- plga: A_LM = W[h] @ A[b,h] + b[h] (fp32), then G^T bf16
  for (int b2 = 0; b2 < B; ++b2)
    gemm64<0, 0><<<dim3(2, 2, 16), 256, 0, stream>>>(plga_W,
        Abuf + (long)b2 * H * DHd * DHd, plga_b, Gb + (long)b2 * H * DHd * DHd,
        DHd, DHd, DHd, DHd, DHd,
        (long)DHd * DHd, (long)DHd * DHd, (long)DHd * DHd, DHd, 1.f);
  plga_g_t<<<(int)(NA / 256), 256, 0, stream>>>(Gb, plga_pw, GTb);

  // ---- qg = q @ G per (b,h): [2048,128] bf16 out
  gemm_bt_mfma<true, false><<<dim3(16, 1, 32), 256, 0, stream>>>(
      qhb, GTb, nullptr, qgb, DHd, DHd, DHd, DHd,
      (long)S * DHd, (long)DHd * DHd, (long)S * DHd, 1.f);

  // ---- attention, chunks of 128 q rows; causal tile-skip
  for (int c = 0; c < S / 128; ++c) {
    const int Kv = (c + 1) * 128;
    gemm_bt_mfma<false, false><<<dim3(1, c + 1, 32), 256, 0, stream>>>(
        qgb + (long)c * 128 * DHd, khb, nullptr, scoresf,
        DHd, DHd, DHd, S, (long)S * DHd, (long)S * DHd, (long)128 * S, SCALE);
    softmax_causal_b<<<32 * 128, 256, 0, stream>>>(scoresf, probsb, c * 128);
    gemm_bt_mfma<true, false><<<dim3(1, 1, 32), 256, 0, stream>>>(
        probsb, vT, nullptr, Hnbh + (long)c * 128 * DHd,
        Kv, S, S, DHd, (long)128 * S, (long)DHd * S, (long)S * DHd, 1.f);
  }

  // ---- back to [B,S,D] and final dense (f32 out)
  untr_b<<<32768, 256, 0, stream>>>(Hnbh, Hnb);
  gemm_bt_mfma<false, true><<<dim3(32, 16, 1), 256, 0, stream>>>(
      Hnb, wdb, dense_b, out, D, D, D, D, 0, 0, 0, 1.f);
}

// Round 4
// 2259.461 us; speedup vs baseline: 2.6529x; 1.0580x over previous
//
#include <hip/hip_runtime.h>
#include <hip/hip_bf16.h>
#include <math.h>

namespace {

constexpr int B = 2, S = 2048, D = 2048, H = 16, DHd = 128, A_DFF = 256;
constexpr int NRES = 8, NDENSE = 2;
constexpr float EPSV = 1e-6f;
constexpr float NEG_SLOPE = 0.2f;
constexpr float SCALE = 0.08838834764831843f; // 1/sqrt(128)

constexpr int TS = 64, KT = 16;

using bf16 = __hip_bfloat16;
using short8 = __attribute__((ext_vector_type(8))) short;
using f32x4  = __attribute__((ext_vector_type(4))) float;

typedef const __attribute__((address_space(1))) unsigned int* gas_ptr;
typedef __attribute__((address_space(3))) unsigned int* las_ptr;

__device__ __forceinline__ void glds16(const void* g, void* l) {
  __builtin_amdgcn_global_load_lds((gas_ptr)g, (las_ptr)l, 16, 0, 0);
}

// ---------------------------------------------------------------------------
// bf16 MFMA GEMM: C[M,N] = scale * (A[M,K] @ Bt[N,K]^T) + bias
// 128x128 tile, BK=32, 256 threads (4 waves), m97 structure.
// ---------------------------------------------------------------------------
template<bool OUT_BF16, bool BIAS>
__global__ __launch_bounds__(256) void gemm_bt_mfma(
    const bf16* __restrict__ A, const bf16* __restrict__ Bt,
    const float* __restrict__ bias, void* __restrict__ Cv,
    int K, int lda, int ldb, int ldc,
    long sA, long sB, long sC, float scale)
{
  A  += (long)blockIdx.z * sA;
  Bt += (long)blockIdx.z * sB;

  __shared__ short As[128 * 32] __attribute__((aligned(16)));
  __shared__ short Bs[128 * 32] __attribute__((aligned(16)));

  const int t = threadIdx.x;
  const int wv = t >> 6, l = t & 63;
  const int m0 = blockIdx.x * 128, n0 = blockIdx.y * 128;

  const int sr = t >> 2, sc = (t & 3) * 8;
  short* ldsA0 = As + wv * 512;
  short* ldsA1 = As + 2048 + wv * 512;
  short* ldsB0 = Bs + wv * 512;
  short* ldsB1 = Bs + 2048 + wv * 512;

  const int wr = wv >> 1, wc = wv & 1;
  const int lr = l & 15, lk = (l >> 4) * 8;

  f32x4 acc[4][4] = {};

  for (int k0 = 0; k0 < K; k0 += 32) {
    __syncthreads();
    glds16(A  + (long)(m0 + sr)      * lda + k0 + sc, ldsA0);
    glds16(A  + (long)(m0 + 64 + sr) * lda + k0 + sc, ldsA1);
    glds16(Bt + (long)(n0 + sr)      * ldb + k0 + sc, ldsB0);
    glds16(Bt + (long)(n0 + 64 + sr) * ldb + k0 + sc, ldsB1);
    __syncthreads();

    short8 af[4], bf[4];
#pragma unroll
    for (int m = 0; m < 4; ++m)
      af[m] = *(const short8*)&As[(wr * 64 + m * 16 + lr) * 32 + lk];
#pragma unroll
    for (int n = 0; n < 4; ++n)
      bf[n] = *(const short8*)&Bs[(wc * 64 + n * 16 + lr) * 32 + lk];
#pragma unroll
    for (int m = 0; m < 4; ++m)
#pragma unroll
      for (int n = 0; n < 4; ++n)
        acc[m][n] = __builtin_amdgcn_mfma_f32_16x16x32_bf16(af[m], bf[n], acc[m][n], 0, 0, 0);
  }

  const int rb = m0 + wr * 64 + (l >> 4) * 4;
  const int cb = n0 + wc * 64 + (l & 15);
#pragma unroll
  for (int m = 0; m < 4; ++m)
#pragma unroll
    for (int n = 0; n < 4; ++n) {
      const int col = cb + n * 16;
      float bv = BIAS ? bias[col] : 0.f;
#pragma unroll
      for (int r = 0; r < 4; ++r) {
        const long off = (long)(rb + m * 16 + r) * ldc + col + blockIdx.z * sC;
        const float c = acc[m][n][r] * scale + bv;
        if (OUT_BF16) ((bf16*)Cv)[off] = __float2bfloat16(c);
        else          ((float*)Cv)[off] = c;
      }
    }
}

// ---------------------------------------------------------------------------
// fp32 GEMM (only used for plga now). MODE 0: C=A@B.
// ---------------------------------------------------------------------------
template<int MODE, int ACT>
__global__ __launch_bounds__(256) void gemm64(
    const float* __restrict__ A, const float* __restrict__ Bm,
    const float* __restrict__ bias, float* __restrict__ C,
    int M, int N, int K, int lda, int ldb,
    long sA, long sB, long sC, long sBias, float scale)
{
  A  += (long)blockIdx.z * sA;
  Bm += (long)blockIdx.z * sB;
  C  += (long)blockIdx.z * sC;
  if (bias) bias += (long)blockIdx.z * sBias;

  __shared__ float As[KT][TS + 4];
  __shared__ float Bs[KT][TS + 4];

  const int t = threadIdx.x;
  const int m0 = blockIdx.x * TS, n0 = blockIdx.y * TS;
  const int tm = (t & 15) * 4;
  const int tn = (t >> 4) * 4;

  float acc[4][4] = {};

  for (int k0 = 0; k0 < K; k0 += KT) {
    if (MODE == 2) {
      const int kk = t >> 6, mm = t & 63;
#pragma unroll
      for (int p = 0; p < 4; ++p)
        As[kk + p * 4][mm] = A[(long)(k0 + kk + p * 4) * lda + m0 + mm];
    } else {
      const int kk = t & 15, mm = t >> 4;
#pragma unroll
      for (int p = 0; p < 4; ++p)
        As[kk][mm + p * 16] = A[(long)(m0 + mm + p * 16) * lda + k0 + kk];
    }
    if (MODE == 1) {
      const int kk = t & 15, nn = t >> 4;
#pragma unroll
      for (int p = 0; p < 4; ++p)
        Bs[kk][nn + p * 16] = Bm[(long)(n0 + nn + p * 16) * ldb + k0 + kk];
    } else {
      const int kk = t >> 6, nn = t & 63;
#pragma unroll
      for (int p = 0; p < 4; ++p)
        Bs[kk + p * 4][nn] = Bm[(long)(k0 + kk + p * 4) * ldb + n0 + nn];
    }
    __syncthreads();

#pragma unroll
    for (int kk = 0; kk < KT; ++kk) {
      float4 av = *(const float4*)&As[kk][tm];
      float4 bv = *(const float4*)&Bs[kk][tn];
      float a[4] = {av.x, av.y, av.z, av.w};
      float b[4] = {bv.x, bv.y, bv.z, bv.w};
#pragma unroll
      for (int i = 0; i < 4; ++i)
#pragma unroll
        for (int j = 0; j < 4; ++j)
          acc[i][j] += a[i] * b[j];
    }
    __syncthreads();
  }

#pragma unroll
  for (int i = 0; i < 4; ++i) {
    const int m = m0 + tm + i;
#pragma unroll
    for (int j = 0; j < 4; ++j) {
      const int n = n0 + tn + j;
      float c = acc[i][j] * scale;
      if (bias) c += bias[n];
      if (ACT == 1) c = c / (1.f + __expf(-c));
      C[(long)m * N + n] = c;
    }
  }
}

// ---------------------------------------------------------------------------
// Fused residual SwiGLU stack. Grid = 32 bh * 8 rowblocks = 256 wgs,
// 256 threads. Each wg owns RROWS=16 rows of one (b,h) 128x128 A matrix,
// runs all NRES*NDENSE dense layers + LNs with A resident in LDS.
// Weights come pre-transposed: w1t,w2t [16][128][256], w3t [16][256][128].
// ---------------------------------------------------------------------------
constexpr int RROWS = 16;
__global__ __launch_bounds__(256) void res_stack(
    float* __restrict__ Abuf,
    const float* __restrict__ w1t, const float* __restrict__ b1,
    const float* __restrict__ w2t, const float* __restrict__ b2,
    const float* __restrict__ w3t, const float* __restrict__ b3,
    const float* __restrict__ lng, const float* __restrict__ lnb)
{
  const int bh = blockIdx.x >> 3;
  const int r0 = (blockIdx.x & 7) * RROWS;
  float* Ag = Abuf + ((long)bh << 14) + (long)r0 * 128;

  __shared__ float Ar[RROWS][128];
  __shared__ float Res[RROWS][128];
  __shared__ float g[RROWS][256];

  const int t = threadIdx.x;
  for (int x = t; x < RROWS * 128; x += 256)
    Ar[x >> 7][x & 127] = Ag[(long)(x >> 7) * 128 + (x & 127)];
  __syncthreads();

  for (int l = 0; l < NRES; ++l) {
    for (int x = t; x < RROWS * 128; x += 256)
      Res[x >> 7][x & 127] = Ar[x >> 7][x & 127];
    __syncthreads();

    for (int n = 0; n < NDENSE; ++n) {
      const long wo = (long)(l * NDENSE + n);
      const float* W1 = w1t + wo * DHd * A_DFF;   // [128][256]
      const float* W2 = w2t + wo * DHd * A_DFF;
      const float* W3 = w3t + wo * A_DFF * DHd;   // [256][128]
      const float bb1 = b1[wo * A_DFF + t];
      const float bb2 = b2[wo * A_DFF + t];

      // x1,x2 for column o=t over all 16 rows
      float a1[RROWS] = {}, a2[RROWS] = {};
      for (int jb = 0; jb < 32; ++jb) {
        float w1v[4], w2v[4];
#pragma unroll
        for (int k = 0; k < 4; ++k) {
          w1v[k] = W1[(long)(jb * 4 + k) * A_DFF + t];
          w2v[k] = W2[(long)(jb * 4 + k) * A_DFF + t];
        }
#pragma unroll
        for (int i = 0; i < RROWS; ++i) {
          const float4 av = *(const float4*)&Ar[i][jb * 4];
          a1[i] += av.x * w1v[0] + av.y * w1v[1] + av.z * w1v[2] + av.w * w1v[3];
          a2[i] += av.x * w2v[0] + av.y * w2v[1] + av.z * w2v[2] + av.w * w2v[3];
        }
      }
#pragma unroll
      for (int i = 0; i < RROWS; ++i) {
        float x1 = a1[i] + bb1;
        x1 = x1 / (1.f + __expf(-x1));
        g[i][t] = x1 * (a2[i] + bb2);
      }
      __syncthreads();

      // A'[i][p] = sum_o g[i][o] * w3[p][o] + b3[p]
      const int p = t & 127, ih = t >> 7;      // ih in {0,1}, i = ih*8..+8
      const float bb3 = b3[wo * DHd + p];
      float a3[8] = {};
      for (int ob = 0; ob < 64; ++ob) {
        float w3v[4];
#pragma unroll
        for (int k = 0; k < 4; ++k)
          w3v[k] = W3[(long)(ob * 4 + k) * DHd + p];
#pragma unroll
        for (int i = 0; i < 8; ++i) {
          const float4 gv = *(const float4*)&g[ih * 8 + i][ob * 4];
          a3[i] += gv.x * w3v[0] + gv.y * w3v[1] + gv.z * w3v[2] + gv.w * w3v[3];
        }
      }
      __syncthreads();
#pragma unroll
      for (int i = 0; i < 8; ++i) Ar[ih * 8 + i][p] = a3[i] + bb3;
      __syncthreads();
    }

    // LN(Ar + Res) per row; wave handles 4 rows, lane covers 2 cols
    {
      const int wv_ = t >> 6, l_ = t & 63;
      for (int i = wv_ * 4; i < wv_ * 4 + 4; ++i) {
        float v0 = Ar[i][l_] + Res[i][l_];
        float v1 = Ar[i][l_ + 64] + Res[i][l_ + 64];
        float s = v0 + v1;
#pragma unroll
        for (int o = 32; o > 0; o >>= 1) s += __shfl_down(s, o);
        const float mu = __shfl(s, 0) * (1.f / 128.f);
        const float d0 = v0 - mu, d1 = v1 - mu;
        float vs = d0 * d0 + d1 * d1;
#pragma unroll
        for (int o = 32; o > 0; o >>= 1) vs += __shfl_down(vs, o);
        const float rstd = rsqrtf(__shfl(vs, 0) * (1.f / 128.f) + EPSV);
        Ar[i][l_]      = d0 * rstd * lng[l * 128 + l_] + lnb[l * 128 + l_];
        Ar[i][l_ + 64] = d1 * rstd * lng[l * 128 + l_ + 64] + lnb[l * 128 + l_ + 64];
      }
    }
    __syncthreads();
  }

  for (int x = t; x < RROWS * 128; x += 256)
    Ag[(long)(x >> 7) * 128 + (x & 127)] = Ar[x >> 7][x & 127];
}

// transpose last two dims: in [L][R][C] -> out [L][C][R]
__global__ __launch_bounds__(256) void tr_w(const float* __restrict__ in,
                                            float* __restrict__ out, int R, int C)
{
  const long idx = (long)blockIdx.x * 256 + threadIdx.x;
  const int r = (int)(idx % R);
  const long tmp = idx / R;
  const int c = (int)(tmp % C);
  const long l = tmp / C;
  out[idx] = in[(l * R + r) * C + c];
}

// f32 -> bf16 convert, 4 elems/thread
__global__ __launch_bounds__(256) void f2b(const float* __restrict__ in,
                                           bf16* __restrict__ out)
{
  const long i = (long)blockIdx.x * 256 + threadIdx.x;
  const float4 v = ((const float4*)in)[i];
  bf16* o = out + i * 4;
  o[0] = __float2bfloat16(v.x); o[1] = __float2bfloat16(v.y);
  o[2] = __float2bfloat16(v.z); o[3] = __float2bfloat16(v.w);
}

// LayerNorm rows of 128 (for ln1), in-place safe.
__global__ __launch_bounds__(64) void ln_row(
    const float* __restrict__ in, const float* __restrict__ g,
    const float* __restrict__ b, float* __restrict__ out)
{
  const long r = blockIdx.x;
  const int t = threadIdx.x;
  float v0 = in[r * 128 + t], v1 = in[r * 128 + t + 64];
  float s = v0 + v1;
#pragma unroll
  for (int o = 32; o > 0; o >>= 1) s += __shfl_down(s, o);
  const float mu = __shfl(s, 0) * (1.f / 128.f);
  const float d0 = v0 - mu, d1 = v1 - mu;
  float vs = d0 * d0 + d1 * d1;
#pragma unroll
  for (int o = 32; o > 0; o >>= 1) vs += __shfl_down(vs, o);
  const float rstd = rsqrtf(__shfl(vs, 0) * (1.f / 128.f) + EPSV);
  out[r * 128 + t]      = d0 * rstd * g[t] + b[t];
  out[r * 128 + t + 64] = d1 * rstd * g[t + 64] + b[t + 64];
}

// [B,S,H,DH] f32 -> [B,H,S,DH] bf16 with RoPE.
__global__ __launch_bounds__(256) void rope_tr2(const float* __restrict__ in,
                                                bf16* __restrict__ outb)
{
  const long idx = (long)blockIdx.x * 256 + threadIdx.x;  // B*S*H*64 pairs
  const int p = idx & 63;
  const int h = (idx >> 6) & (H - 1);
  const int s = (idx >> 10) & (S - 1);
  const int b = (int)(idx >> 21);
  const float theta = powf(10000.f, -(float)p * (1.f / 64.f));
  float sn, cs;
  sincosf((float)s * theta, &sn, &cs);
  const long src = (((long)(b * S + s) * H + h) << 7) + 2 * p;
  const float x1 = in[src], x2 = in[src + 1];
  const long dst = (((long)(b * H + h) * S + s) << 7) + 2 * p;
  outb[dst]     = __float2bfloat16(x1 * cs - x2 * sn);
  outb[dst + 1] = __float2bfloat16(x2 * cs + x1 * sn);
}

// bf16 tiled transpose: [BH][S][128] -> [BH][128][S], 64x64 tiles
__global__ __launch_bounds__(256) void tr_qT(const bf16* __restrict__ in,
                                             bf16* __restrict__ outT)
{
  __shared__ unsigned short tile[64][68];
  const int t = threadIdx.x;
  const int s0 = blockIdx.x * 64, d0 = blockIdx.y * 64;
  const long bh = blockIdx.z;
  const unsigned short* ip = (const unsigned short*)in + (bh * S + s0) * 128 + d0;
  unsigned short* op = (unsigned short*)outT + (bh * 128 + d0) * S + s0;
  const int r = t >> 4, c = (t & 15) * 4;
#pragma unroll
  for (int p = 0; p < 4; ++p) {
    const ushort4 v = *(const ushort4*)&ip[(long)(r + p * 16) * 128 + c];
    tile[r + p * 16][c]     = v.x;
    tile[r + p * 16][c + 1] = v.y;
    tile[r + p * 16][c + 2] = v.z;
    tile[r + p * 16][c + 3] = v.w;
  }
  __syncthreads();
#pragma unroll
  for (int p = 0; p < 4; ++p) {
    ushort4 w;
    w.x = tile[c][r + p * 16];
    w.y = tile[c + 1][r + p * 16];
    w.z = tile[c + 2][r + p * 16];
    w.w = tile[c + 3][r + p * 16];
    *(ushort4*)&op[(long)(r + p * 16) * S + c] = w;
  }
}

// [B,S,H,DH] f32 -> vT bf16 [B,H,DH,S]
__global__ __launch_bounds__(256) void tr_v_b(const float* __restrict__ in,
                                              bf16* __restrict__ out)
{
  const long idx = (long)blockIdx.x * 256 + threadIdx.x;
  const int s = idx & (S - 1);
  const int dh = (idx >> 11) & 127;
  const int h = (idx >> 18) & (H - 1);
  const int b = (int)(idx >> 22);
  out[idx] = __float2bfloat16(in[(((long)(b * S + s) * H + h) << 7) + dh]);
}

// Hnbh bf16 [B,H,S,DH] -> Hnb bf16 [B,S,H*DH]
__global__ __launch_bounds__(256) void untr_b(const bf16* __restrict__ in,
                                              bf16* __restrict__ out)
{
  const long idx = (long)blockIdx.x * 256 + threadIdx.x;
  const int d = idx & 127;
  const int h = (idx >> 7) & (H - 1);
  const int s = (idx >> 11) & (S - 1);
  const int b = (int)(idx >> 22);
  out[idx] = in[(((long)(b * H + h) * S + s) << 7) + d];
}

// G = sign/pow(leaky_relu(A_LM)); reads Gb f32 [bh,d,f], writes bf16 G^T [bh,f,d]
__global__ __launch_bounds__(256) void plga_g_t(const float* __restrict__ a,
                                                const float* __restrict__ pw,
                                                bf16* __restrict__ gt)
{
  const long idx = (long)blockIdx.x * 256 + threadIdx.x;
  const int f = idx & 127;
  const int dd = (idx >> 7) & 127;
  const int bh = (int)(idx >> 14);
  const int h = bh & (H - 1);
  float x = a[idx];
  x = x > 0.f ? x : NEG_SLOPE * x;
  const float gq = powf(fabsf(x) + EPSV, pw[h]);
  const float gv = x > 0.f ? gq : (x < 0.f ? -gq : 0.f);
  gt[((long)bh << 14) + f * 128 + dd] = __float2bfloat16(gv);
}

// causal softmax: f32 scores chunk [32*128][S] -> bf16 probs over [0,Kv)
__global__ __launch_bounds__(256) void softmax_causal_b(
    const float* __restrict__ sc, bf16* __restrict__ pb, int chunk0)
{
  const int r = blockIdx.x;
  const int sl = r & 127;
  const int valid = chunk0 + sl + 1;
  const int Kv = chunk0 + 128;
  const float* row = sc + (long)r * S;
  bf16* prow = pb + (long)r * S;
  const int t = threadIdx.x;
  __shared__ float red[256];

  float mx = -1e30f;
  for (int i = t; i < valid; i += 256) mx = fmaxf(mx, row[i]);
  red[t] = mx; __syncthreads();
  for (int o = 128; o > 0; o >>= 1) { if (t < o) red[t] = fmaxf(red[t], red[t + o]); __syncthreads(); }
  mx = red[0]; __syncthreads();

  float sum = 0.f;
  for (int i = t; i < valid; i += 256) sum += __expf(row[i] - mx);
  red[t] = sum; __syncthreads();
  for (int o = 128; o > 0; o >>= 1) { if (t < o) red[t] += red[t + o]; __syncthreads(); }
  const float inv = 1.f / red[0];

  for (int i = t; i < valid; i += 256) prow[i] = __float2bfloat16(__expf(row[i] - mx) * inv);
  for (int i = valid + t; i < Kv; i += 256) prow[i] = __float2bfloat16(0.f);
}

}  // namespace

extern "C" void kernel_launch(void* const* d_in, const int* in_sizes, int n_in,
                              void* d_out, int out_size, void* d_ws, size_t ws_size,
                              hipStream_t stream)
{
  const float* q_in    = (const float*)d_in[0];
  const float* k_in    = (const float*)d_in[1];
  const float* v_in    = (const float*)d_in[2];
  const float* wq_w    = (const float*)d_in[4];
  const float* wq_b    = (const float*)d_in[5];
  const float* wk_w    = (const float*)d_in[6];
  const float* wk_b    = (const float*)d_in[7];
  const float* wv_w    = (const float*)d_in[8];
  const float* wv_b    = (const float*)d_in[9];
  const float* dense_w = (const float*)d_in[10];
  const float* dense_b = (const float*)d_in[11];
  const float* ln1_g   = (const float*)d_in[12];
  const float* ln1_b   = (const float*)d_in[13];
  const float* res_w1  = (const float*)d_in[14];
  const float* res_b1  = (const float*)d_in[15];
  const float* res_w2  = (const float*)d_in[16];
  const float* res_b2  = (const float*)d_in[17];
  const float* res_w3  = (const float*)d_in[18];
  const float* res_b3  = (const float*)d_in[19];
  const float* res_lng = (const float*)d_in[20];
  const float* res_lnb = (const float*)d_in[21];
  const float* plga_W  = (const float*)d_in[22];
  const float* plga_b  = (const float*)d_in[23];
  const float* plga_pw = (const float*)d_in[24];
  float* out = (float*)d_out;

  const long NBS = (long)B * S * D;            // 8388608
  const long NA  = (long)B * H * DHd * DHd;    // 524288
  const long DDw = (long)D * D;                // 4194304
  const long NW  = (long)NRES * NDENSE * A_DFF * DHd;  // 524288

  float* ws = (float*)d_ws;
  float* qp = ws;               // q proj f32; later probs bf16
  float* kp = ws + NBS;         // k proj f32; later Hnbh/Hnb bf16
  float* vp = ws + 2 * NBS;     // v proj f32; later Abuf/Gb f32, then scores
  float* qhslot = ws + 3 * NBS; // qTb bf16 (1st half), GTb bf16 (2nd half)
  float* Abuf = vp;
  float* Gb   = vp + NA;
  float* scoresf = vp;

  bf16* bbase = (bf16*)(ws + 4 * NBS);
  bf16* qb  = bbase;            // q_in bf16; later qhb (rope'd heads)
  bf16* kb  = bbase + NBS;      // k_in bf16; later khb
  bf16* vb  = bbase + 2 * NBS;  // v_in bf16; later vT
  bf16* wqb = bbase + 3 * NBS;  // later qgb
  bf16* wkb = wqb + DDw;
  bf16* wvb = wqb + 2 * DDw;    // later wdb
  bf16* qhb = qb;
  bf16* khb = kb;
  bf16* vT  = vb;
  bf16* qgb = wqb;
  bf16* wdb = wvb;
  bf16* qTb = (bf16*)qhslot;
  bf16* GTb = (bf16*)qhslot + NBS;
  bf16* probsb = (bf16*)qp;
  bf16* Hnbh = (bf16*)kp;
  bf16* Hnb  = Hnbh + NBS;
  float* w1t = (float*)(bbase + 3 * NBS + 3 * DDw);  // [16][128][256]
  float* w2t = w1t + NW;
  float* w3t = w2t + NW;

  // ---- convert inputs + weights to bf16; transpose stack weights
  f2b<<<(int)(NBS / 1024), 256, 0, stream>>>(q_in, qb);
  f2b<<<(int)(NBS / 1024), 256, 0, stream>>>(k_in, kb);
  f2b<<<(int)(NBS / 1024), 256, 0, stream>>>(v_in, vb);
  f2b<<<(int)(DDw / 1024), 256, 0, stream>>>(wq_w, wqb);
  f2b<<<(int)(DDw / 1024), 256, 0, stream>>>(wk_w, wkb);
  f2b<<<(int)(DDw / 1024), 256, 0, stream>>>(wv_w, wvb);
  tr_w<<<(int)(NW / 256), 256, 0, stream>>>(res_w1, w1t, A_DFF, DHd);
  tr_w<<<(int)(NW / 256), 256, 0, stream>>>(res_w2, w2t, A_DFF, DHd);
  tr_w<<<(int)(NW / 256), 256, 0, stream>>>(res_w3, w3t, DHd, A_DFF);

  // ---- QKV projections (bf16 MFMA)
  gemm_bt_mfma<false, true><<<dim3(32, 16, 1), 256, 0, stream>>>(
      qb, wqb, wq_b, qp, D, D, D, D, 0, 0, 0, 1.f);
  gemm_bt_mfma<false, true><<<dim3(32, 16, 1), 256, 0, stream>>>(
      kb, wkb, wk_b, kp, D, D, D, D, 0, 0, 0, 1.f);
  gemm_bt_mfma<false, true><<<dim3(32, 16, 1), 256, 0, stream>>>(
      vb, wvb, wv_b, vp, D, D, D, D, 0, 0, 0, 1.f);

  f2b<<<(int)(DDw / 1024), 256, 0, stream>>>(dense_w, wdb);

  // ---- RoPE + head transposes
  rope_tr2<<<16384, 256, 0, stream>>>(qp, qhb);
  rope_tr2<<<16384, 256, 0, stream>>>(kp, khb);
  tr_v_b<<<32768, 256, 0, stream>>>(vp, vT);
  tr_qT<<<dim3(32, 2, 32), 256, 0, stream>>>(qhb, qTb);

  // ---- metric A = q^T q per (b,h)  (bf16 MFMA, K=S)
  gemm_bt_mfma<false, false><<<dim3(1, 1, 32), 256, 0, stream>>>(
      qTb, qTb, nullptr, Abuf, S, S, S, DHd,
      (long)DHd * S, (long)DHd * S, (long)DHd * DHd, 1.f);
  ln_row<<<B * H * DHd, 64, 0, stream>>>(Abuf, ln1_g, ln1_b, Abuf);

  // ---- fused residual SwiGLU stack (fp32, one dispatch)
  res_stack<<<256, 256, 0, stream>>>(Abuf, w1t, res_b1, w2t, res_b2,
                                     w3t, res_b3, res_lng, res_lnb);

  // ---- plga: A_LM = W[h] @ A[b,h] + b[h] (fp32), then G^T bf16
  for (int b2 = 0; b2 < B; ++b2)
    gemm64<0, 0><<<dim3(2, 2, 16), 256, 0, stream>>>(plga_W,
        Abuf + (long)b2 * H * DHd * DHd, plga_b, Gb + (long)b2 * H * DHd * DHd,
        DHd, DHd, DHd, DHd, DHd,
        (long)DHd * DHd, (long)DHd * DHd, (long)DHd * DHd, DHd, 1.f);
  plga_g_t<<<(int)(NA / 256), 256, 0, stream>>>(Gb, plga_pw, GTb);

  // ---- qg = q @ G per (b,h)
  gemm_bt_mfma<true, false><<<dim3(16, 1, 32), 256, 0, stream>>>(
      qhb, GTb, nullptr, qgb, DHd, DHd, DHd, DHd,
      (long)S * DHd, (long)DHd * DHd, (long)S * DHd, 1.f);

  // ---- attention, chunks of 128 q rows; causal tile-skip
  for (int c = 0; c < S / 128; ++c) {
    const int Kv = (c + 1) * 128;
    gemm_bt_mfma<false, false><<<dim3(1, c + 1, 32), 256, 0, stream>>>(
        qgb + (long)c * 128 * DHd, khb, nullptr, scoresf,
        DHd, DHd, DHd, S, (long)S * DHd, (long)S * DHd, (long)128 * S, SCALE);
    softmax_causal_b<<<32 * 128, 256, 0, stream>>>(scoresf, probsb, c * 128);
    gemm_bt_mfma<true, false><<<dim3(1, 1, 32), 256, 0, stream>>>(
        probsb, vT, nullptr, Hnbh + (long)c * 128 * DHd,
        Kv, S, S, DHd, (long)128 * S, (long)DHd * S, (long)S * DHd, 1.f);
  }

  // ---- back to [B,S,D] and final dense (f32 out)
  untr_b<<<32768, 256, 0, stream>>>(Hnbh, Hnb);
  gemm_bt_mfma<false, true><<<dim3(32, 16, 1), 256, 0, stream>>>(
      Hnb, wdb, dense_b, out, D, D, D, D, 0, 0, 0, 1.f);
}

// Round 5
// 1738.541 us; speedup vs baseline: 3.4478x; 1.2996x over previous
//
#include <hip/hip_runtime.h>
#include <hip/hip_bf16.h>
#include <math.h>

namespace {

constexpr int B = 2, S = 2048, D = 2048, H = 16, DHd = 128, A_DFF = 256;
constexpr int NRES = 8, NDENSE = 2;
constexpr float EPSV = 1e-6f;
constexpr float NEG_SLOPE = 0.2f;
constexpr float SCALE = 0.08838834764831843f; // 1/sqrt(128)

constexpr int TS = 64, KT = 16;
constexpr int KSPLIT = 8;

using bf16 = __hip_bfloat16;
using short8 = __attribute__((ext_vector_type(8))) short;
using f32x4  = __attribute__((ext_vector_type(4))) float;

typedef const __attribute__((address_space(1))) unsigned int* gas_ptr;
typedef __attribute__((address_space(3))) unsigned int* las_ptr;

__device__ __forceinline__ void glds16(const void* g, void* l) {
  __builtin_amdgcn_global_load_lds((gas_ptr)g, (las_ptr)l, 16, 0, 0);
}

// ---------------------------------------------------------------------------
// bf16 MFMA GEMM: C[M,N] = scale * (A[M,K] @ Bt[N,K]^T) + bias
// 128x128 tile, BK=32, 256 threads (4 waves), m97 structure.
// ---------------------------------------------------------------------------
template<bool OUT_BF16, bool BIAS>
__global__ __launch_bounds__(256) void gemm_bt_mfma(
    const bf16* __restrict__ A, const bf16* __restrict__ Bt,
    const float* __restrict__ bias, void* __restrict__ Cv,
    int K, int lda, int ldb, int ldc,
    long sA, long sB, long sC, float scale)
{
  A  += (long)blockIdx.z * sA;
  Bt += (long)blockIdx.z * sB;

  __shared__ short As[128 * 32] __attribute__((aligned(16)));
  __shared__ short Bs[128 * 32] __attribute__((aligned(16)));

  const int t = threadIdx.x;
  const int wv = t >> 6, l = t & 63;
  const int m0 = blockIdx.x * 128, n0 = blockIdx.y * 128;

  const int sr = t >> 2, sc = (t & 3) * 8;
  short* ldsA0 = As + wv * 512;
  short* ldsA1 = As + 2048 + wv * 512;
  short* ldsB0 = Bs + wv * 512;
  short* ldsB1 = Bs + 2048 + wv * 512;

  const int wr = wv >> 1, wc = wv & 1;
  const int lr = l & 15, lk = (l >> 4) * 8;

  f32x4 acc[4][4] = {};

  for (int k0 = 0; k0 < K; k0 += 32) {
    __syncthreads();
    glds16(A  + (long)(m0 + sr)      * lda + k0 + sc, ldsA0);
    glds16(A  + (long)(m0 + 64 + sr) * lda + k0 + sc, ldsA1);
    glds16(Bt + (long)(n0 + sr)      * ldb + k0 + sc, ldsB0);
    glds16(Bt + (long)(n0 + 64 + sr) * ldb + k0 + sc, ldsB1);
    __syncthreads();

    short8 af[4], bf[4];
#pragma unroll
    for (int m = 0; m < 4; ++m)
      af[m] = *(const short8*)&As[(wr * 64 + m * 16 + lr) * 32 + lk];
#pragma unroll
    for (int n = 0; n < 4; ++n)
      bf[n] = *(const short8*)&Bs[(wc * 64 + n * 16 + lr) * 32 + lk];
#pragma unroll
    for (int m = 0; m < 4; ++m)
#pragma unroll
      for (int n = 0; n < 4; ++n)
        acc[m][n] = __builtin_amdgcn_mfma_f32_16x16x32_bf16(af[m], bf[n], acc[m][n], 0, 0, 0);
  }

  const int rb = m0 + wr * 64 + (l >> 4) * 4;
  const int cb = n0 + wc * 64 + (l & 15);
#pragma unroll
  for (int m = 0; m < 4; ++m)
#pragma unroll
    for (int n = 0; n < 4; ++n) {
      const int col = cb + n * 16;
      float bv = BIAS ? bias[col] : 0.f;
#pragma unroll
      for (int r = 0; r < 4; ++r) {
        const long off = (long)(rb + m * 16 + r) * ldc + col + blockIdx.z * sC;
        const float c = acc[m][n][r] * scale + bv;
        if (OUT_BF16) ((bf16*)Cv)[off] = __float2bfloat16(c);
        else          ((float*)Cv)[off] = c;
      }
    }
}

// ---------------------------------------------------------------------------
// A = qT @ qT^T per (b,h), split-K over KSPLIT chunks, f32 atomicAdd output.
// qT layout [bh][128][S]. grid = (KSPLIT, 1, 32). Output must be pre-zeroed.
// ---------------------------------------------------------------------------
__global__ __launch_bounds__(256) void qtq_splitk(
    const bf16* __restrict__ qT, float* __restrict__ Aout)
{
  const int ks = blockIdx.x;
  const long bh = blockIdx.z;
  const bf16* Ab = qT + (bh << 7) * S;
  float* Cf = Aout + (bh << 14);

  __shared__ short As[128 * 32] __attribute__((aligned(16)));

  const int t = threadIdx.x;
  const int wv = t >> 6, l = t & 63;
  const int sr = t >> 2, sc = (t & 3) * 8;
  short* ldsA0 = As + wv * 512;
  short* ldsA1 = As + 2048 + wv * 512;

  const int wr = wv >> 1, wc = wv & 1;
  const int lr = l & 15, lk = (l >> 4) * 8;

  f32x4 acc[4][4] = {};

  const int kbeg = ks * (S / KSPLIT), kend = kbeg + S / KSPLIT;
  for (int k0 = kbeg; k0 < kend; k0 += 32) {
    __syncthreads();
    glds16(Ab + (long)sr * S + k0 + sc, ldsA0);        // A tile == B tile
    glds16(Ab + (long)(64 + sr) * S + k0 + sc, ldsA1);
    __syncthreads();

    short8 af[4], bf[4];
#pragma unroll
    for (int m = 0; m < 4; ++m)
      af[m] = *(const short8*)&As[(wr * 64 + m * 16 + lr) * 32 + lk];
#pragma unroll
    for (int n = 0; n < 4; ++n)
      bf[n] = *(const short8*)&As[(wc * 64 + n * 16 + lr) * 32 + lk];
#pragma unroll
    for (int m = 0; m < 4; ++m)
#pragma unroll
      for (int n = 0; n < 4; ++n)
        acc[m][n] = __builtin_amdgcn_mfma_f32_16x16x32_bf16(af[m], bf[n], acc[m][n], 0, 0, 0);
  }

  const int rb = wr * 64 + (l >> 4) * 4;
  const int cb = wc * 64 + (l & 15);
#pragma unroll
  for (int m = 0; m < 4; ++m)
#pragma unroll
    for (int n = 0; n < 4; ++n)
#pragma unroll
      for (int r = 0; r < 4; ++r)
        atomicAdd(&Cf[(long)(rb + m * 16 + r) * 128 + cb + n * 16], acc[m][n][r]);
}

// ---------------------------------------------------------------------------
// fp32 GEMM (only used for plga). MODE 0: C=A@B.
// ---------------------------------------------------------------------------
template<int MODE, int ACT>
__global__ __launch_bounds__(256) void gemm64(
    const float* __restrict__ A, const float* __restrict__ Bm,
    const float* __restrict__ bias, float* __restrict__ C,
    int M, int N, int K, int lda, int ldb,
    long sA, long sB, long sC, long sBias, float scale)
{
  A  += (long)blockIdx.z * sA;
  Bm += (long)blockIdx.z * sB;
  C  += (long)blockIdx.z * sC;
  if (bias) bias += (long)blockIdx.z * sBias;

  __shared__ float As[KT][TS + 4];
  __shared__ float Bs[KT][TS + 4];

  const int t = threadIdx.x;
  const int m0 = blockIdx.x * TS, n0 = blockIdx.y * TS;
  const int tm = (t & 15) * 4;
  const int tn = (t >> 4) * 4;

  float acc[4][4] = {};

  for (int k0 = 0; k0 < K; k0 += KT) {
    if (MODE == 2) {
      const int kk = t >> 6, mm = t & 63;
#pragma unroll
      for (int p = 0; p < 4; ++p)
        As[kk + p * 4][mm] = A[(long)(k0 + kk + p * 4) * lda + m0 + mm];
    } else {
      const int kk = t & 15, mm = t >> 4;
#pragma unroll
      for (int p = 0; p < 4; ++p)
        As[kk][mm + p * 16] = A[(long)(m0 + mm + p * 16) * lda + k0 + kk];
    }
    if (MODE == 1) {
      const int kk = t & 15, nn = t >> 4;
#pragma unroll
      for (int p = 0; p < 4; ++p)
        Bs[kk][nn + p * 16] = Bm[(long)(n0 + nn + p * 16) * ldb + k0 + kk];
    } else {
      const int kk = t >> 6, nn = t & 63;
#pragma unroll
      for (int p = 0; p < 4; ++p)
        Bs[kk + p * 4][nn] = Bm[(long)(k0 + kk + p * 4) * ldb + n0 + nn];
    }
    __syncthreads();

#pragma unroll
    for (int kk = 0; kk < KT; ++kk) {
      float4 av = *(const float4*)&As[kk][tm];
      float4 bv = *(const float4*)&Bs[kk][tn];
      float a[4] = {av.x, av.y, av.z, av.w};
      float b[4] = {bv.x, bv.y, bv.z, bv.w};
#pragma unroll
      for (int i = 0; i < 4; ++i)
#pragma unroll
        for (int j = 0; j < 4; ++j)
          acc[i][j] += a[i] * b[j];
    }
    __syncthreads();
  }

#pragma unroll
  for (int i = 0; i < 4; ++i) {
    const int m = m0 + tm + i;
#pragma unroll
    for (int j = 0; j < 4; ++j) {
      const int n = n0 + tn + j;
      float c = acc[i][j] * scale;
      if (bias) c += bias[n];
      if (ACT == 1) c = c / (1.f + __expf(-c));
      C[(long)m * N + n] = c;
    }
  }
}

// ---------------------------------------------------------------------------
// Fused residual SwiGLU stack. RROWS=8: grid = 32 bh * 16 rowblocks = 512 wgs
// (2 blocks/CU, 8 waves/CU). Each wg owns 8 rows of one (b,h) 128x128 A,
// runs all 16 dense layers + 8 LNs with rows resident in LDS (16 KB).
// Weight loads are 2-stage software-pipelined (named reg sets, static idx).
// Weights pre-transposed: w1t,w2t [16][128][256], w3t [16][256][128].
// ---------------------------------------------------------------------------
constexpr int RROWS = 8;
__global__ __launch_bounds__(256, 2) void res_stack(
    float* __restrict__ Abuf,
    const float* __restrict__ w1t, const float* __restrict__ b1,
    const float* __restrict__ w2t, const float* __restrict__ b2,
    const float* __restrict__ w3t, const float* __restrict__ b3,
    const float* __restrict__ lng, const float* __restrict__ lnb)
{
  const int bh = blockIdx.x >> 4;
  const int r0 = (blockIdx.x & 15) * RROWS;
  float* Ag = Abuf + ((long)bh << 14) + (long)r0 * 128;

  __shared__ float Ar[RROWS][128];
  __shared__ float Res[RROWS][128];
  __shared__ float g[RROWS][256];

  const int t = threadIdx.x;
  for (int x = t; x < RROWS * 128; x += 256)
    Ar[x >> 7][x & 127] = Ag[(long)(x >> 7) * 128 + (x & 127)];
  __syncthreads();

  for (int l = 0; l < NRES; ++l) {
    for (int x = t; x < RROWS * 128; x += 256)
      Res[x >> 7][x & 127] = Ar[x >> 7][x & 127];
    __syncthreads();

    for (int n = 0; n < NDENSE; ++n) {
      const long wo = (long)(l * NDENSE + n);
      const float* W1 = w1t + wo * DHd * A_DFF;   // [128][256]
      const float* W2 = w2t + wo * DHd * A_DFF;
      const float* W3 = w3t + wo * A_DFF * DHd;   // [256][128]
      const float bb1 = b1[wo * A_DFF + t];
      const float bb2 = b2[wo * A_DFF + t];

      // ---- part 1: x1,x2 for column o=t over 8 rows (2-stage prefetch)
      float a1[RROWS] = {}, a2[RROWS] = {};
      float w1a[4], w2a[4], w1b[4], w2b[4];
#pragma unroll
      for (int k = 0; k < 4; ++k) {
        w1a[k] = W1[(long)k * A_DFF + t];
        w2a[k] = W2[(long)k * A_DFF + t];
      }
      for (int jb = 0; jb < 32; jb += 2) {
#pragma unroll
        for (int k = 0; k < 4; ++k) {
          w1b[k] = W1[(long)((jb + 1) * 4 + k) * A_DFF + t];
          w2b[k] = W2[(long)((jb + 1) * 4 + k) * A_DFF + t];
        }
#pragma unroll
        for (int i = 0; i < RROWS; ++i) {
          const float4 av = *(const float4*)&Ar[i][jb * 4];
          a1[i] += av.x * w1a[0] + av.y * w1a[1] + av.z * w1a[2] + av.w * w1a[3];
          a2[i] += av.x * w2a[0] + av.y * w2a[1] + av.z * w2a[2] + av.w * w2a[3];
        }
        if (jb + 2 < 32) {
#pragma unroll
          for (int k = 0; k < 4; ++k) {
            w1a[k] = W1[(long)((jb + 2) * 4 + k) * A_DFF + t];
            w2a[k] = W2[(long)((jb + 2) * 4 + k) * A_DFF + t];
          }
        }
#pragma unroll
        for (int i = 0; i < RROWS; ++i) {
          const float4 av = *(const float4*)&Ar[i][jb * 4 + 4];
          a1[i] += av.x * w1b[0] + av.y * w1b[1] + av.z * w1b[2] + av.w * w1b[3];
          a2[i] += av.x * w2b[0] + av.y * w2b[1] + av.z * w2b[2] + av.w * w2b[3];
        }
      }
#pragma unroll
      for (int i = 0; i < RROWS; ++i) {
        float x1 = a1[i] + bb1;
        x1 = x1 / (1.f + __expf(-x1));
        g[i][t] = x1 * (a2[i] + bb2);
      }
      __syncthreads();

      // ---- part 2: A'[i][p] = sum_o g[i][o] * w3t[o][p] + b3[p]
      const int p = t & 127, ih = t >> 7;      // ih in {0,1}, rows ih*4..+4
      const float bb3 = b3[wo * DHd + p];
      float a3[4] = {};
      float w3a[4], w3b[4];
#pragma unroll
      for (int k = 0; k < 4; ++k) w3a[k] = W3[(long)k * DHd + p];
      for (int ob = 0; ob < 64; ob += 2) {
#pragma unroll
        for (int k = 0; k < 4; ++k)
          w3b[k] = W3[(long)((ob + 1) * 4 + k) * DHd + p];
#pragma unroll
        for (int i = 0; i < 4; ++i) {
          const float4 gv = *(const float4*)&g[ih * 4 + i][ob * 4];
          a3[i] += gv.x * w3a[0] + gv.y * w3a[1] + gv.z * w3a[2] + gv.w * w3a[3];
        }
        if (ob + 2 < 64) {
#pragma unroll
          for (int k = 0; k < 4; ++k)
            w3a[k] = W3[(long)((ob + 2) * 4 + k) * DHd + p];
        }
#pragma unroll
        for (int i = 0; i < 4; ++i) {
          const float4 gv = *(const float4*)&g[ih * 4 + i][ob * 4 + 4];
          a3[i] += gv.x * w3b[0] + gv.y * w3b[1] + gv.z * w3b[2] + gv.w * w3b[3];
        }
      }
      __syncthreads();
#pragma unroll
      for (int i = 0; i < 4; ++i) Ar[ih * 4 + i][p] = a3[i] + bb3;
      __syncthreads();
    }

    // LN(Ar + Res) per row; each wave handles 2 rows
    {
      const int wv_ = t >> 6, l_ = t & 63;
#pragma unroll
      for (int i = wv_ * 2; i < wv_ * 2 + 2; ++i) {
        float v0 = Ar[i][l_] + Res[i][l_];
        float v1 = Ar[i][l_ + 64] + Res[i][l_ + 64];
        float s = v0 + v1;
#pragma unroll
        for (int o = 32; o > 0; o >>= 1) s += __shfl_down(s, o);
        const float mu = __shfl(s, 0) * (1.f / 128.f);
        const float d0 = v0 - mu, d1 = v1 - mu;
        float vs = d0 * d0 + d1 * d1;
#pragma unroll
        for (int o = 32; o > 0; o >>= 1) vs += __shfl_down(vs, o);
        const float rstd = rsqrtf(__shfl(vs, 0) * (1.f / 128.f) + EPSV);
        Ar[i][l_]      = d0 * rstd * lng[l * 128 + l_] + lnb[l * 128 + l_];
        Ar[i][l_ + 64] = d1 * rstd * lng[l * 128 + l_ + 64] + lnb[l * 128 + l_ + 64];
      }
    }
    __syncthreads();
  }

  for (int x = t; x < RROWS * 128; x += 256)
    Ag[(long)(x >> 7) * 128 + (x & 127)] = Ar[x >> 7][x & 127];
}

// transpose last two dims: in [L][R][C] -> out [L][C][R]
__global__ __launch_bounds__(256) void tr_w(const float* __restrict__ in,
                                            float* __restrict__ out, int R, int C)
{
  const long idx = (long)blockIdx.x * 256 + threadIdx.x;
  const int r = (int)(idx % R);
  const long tmp = idx / R;
  const int c = (int)(tmp % C);
  const long l = tmp / C;
  out[idx] = in[(l * R + r) * C + c];
}

// f32 -> bf16 convert, 4 elems/thread
__global__ __launch_bounds__(256) void f2b(const float* __restrict__ in,
                                           bf16* __restrict__ out)
{
  const long i = (long)blockIdx.x * 256 + threadIdx.x;
  const float4 v = ((const float4*)in)[i];
  bf16* o = out + i * 4;
  o[0] = __float2bfloat16(v.x); o[1] = __float2bfloat16(v.y);
  o[2] = __float2bfloat16(v.z); o[3] = __float2bfloat16(v.w);
}

// LayerNorm rows of 128 (for ln1), in-place safe.
__global__ __launch_bounds__(64) void ln_row(
    const float* __restrict__ in, const float* __restrict__ g,
    const float* __restrict__ b, float* __restrict__ out)
{
  const long r = blockIdx.x;
  const int t = threadIdx.x;
  float v0 = in[r * 128 + t], v1 = in[r * 128 + t + 64];
  float s = v0 + v1;
#pragma unroll
  for (int o = 32; o > 0; o >>= 1) s += __shfl_down(s, o);
  const float mu = __shfl(s, 0) * (1.f / 128.f);
  const float d0 = v0 - mu, d1 = v1 - mu;
  float vs = d0 * d0 + d1 * d1;
#pragma unroll
  for (int o = 32; o > 0; o >>= 1) vs += __shfl_down(vs, o);
  const float rstd = rsqrtf(__shfl(vs, 0) * (1.f / 128.f) + EPSV);
  out[r * 128 + t]      = d0 * rstd * g[t] + b[t];
  out[r * 128 + t + 64] = d1 * rstd * g[t + 64] + b[t + 64];
}

// [B,S,H,DH] f32 -> [B,H,S,DH] bf16 with RoPE.
__global__ __launch_bounds__(256) void rope_tr2(const float* __restrict__ in,
                                                bf16* __restrict__ outb)
{
  const long idx = (long)blockIdx.x * 256 + threadIdx.x;  // B*S*H*64 pairs
  const int p = idx & 63;
  const int h = (idx >> 6) & (H - 1);
  const int s = (idx >> 10) & (S - 1);
  const int b = (int)(idx >> 21);
  const float theta = powf(10000.f, -(float)p * (1.f / 64.f));
  float sn, cs;
  sincosf((float)s * theta, &sn, &cs);
  const long src = (((long)(b * S + s) * H + h) << 7) + 2 * p;
  const float x1 = in[src], x2 = in[src + 1];
  const long dst = (((long)(b * H + h) * S + s) << 7) + 2 * p;
  outb[dst]     = __float2bfloat16(x1 * cs - x2 * sn);
  outb[dst + 1] = __float2bfloat16(x2 * cs + x1 * sn);
}

// bf16 tiled transpose: [BH][S][128] -> [BH][128][S], 64x64 tiles
__global__ __launch_bounds__(256) void tr_qT(const bf16* __restrict__ in,
                                             bf16* __restrict__ outT)
{
  __shared__ unsigned short tile[64][68];
  const int t = threadIdx.x;
  const int s0 = blockIdx.x * 64, d0 = blockIdx.y * 64;
  const long bh = blockIdx.z;
  const unsigned short* ip = (const unsigned short*)in + (bh * S + s0) * 128 + d0;
  unsigned short* op = (unsigned short*)outT + (bh * 128 + d0) * S + s0;
  const int r = t >> 4, c = (t & 15) * 4;
#pragma unroll
  for (int p = 0; p < 4; ++p) {
    const ushort4 v = *(const ushort4*)&ip[(long)(r + p * 16) * 128 + c];
    tile[r + p * 16][c]     = v.x;
    tile[r + p * 16][c + 1] = v.y;
    tile[r + p * 16][c + 2] = v.z;
    tile[r + p * 16][c + 3] = v.w;
  }
  __syncthreads();
#pragma unroll
  for (int p = 0; p < 4; ++p) {
    ushort4 w;
    w.x = tile[c][r + p * 16];
    w.y = tile[c + 1][r + p * 16];
    w.z = tile[c + 2][r + p * 16];
    w.w = tile[c + 3][r + p * 16];
    *(ushort4*)&op[(long)(r + p * 16) * S + c] = w;
  }
}

// [B,S,H,DH] f32 -> vT bf16 [B,H,DH,S]
__global__ __launch_bounds__(256) void tr_v_b(const float* __restrict__ in,
                                              bf16* __restrict__ out)
{
  const long idx = (long)blockIdx.x * 256 + threadIdx.x;
  const int s = idx & (S - 1);
  const int dh = (idx >> 11) & 127;
  const int h = (idx >> 18) & (H - 1);
  const int b = (int)(idx >> 22);
  out[idx] = __float2bfloat16(in[(((long)(b * S + s) * H + h) << 7) + dh]);
}

// Hnbh bf16 [B,H,S,DH] -> Hnb bf16 [B,S,H*DH]
__global__ __launch_bounds__(256) void untr_b(const bf16* __restrict__ in,
                                              bf16* __restrict__ out)
{
  const long idx = (long)blockIdx.x * 256 + threadIdx.x;
  const int d = idx & 127;
  const int h = (idx >> 7) & (H - 1);
  const int s = (idx >> 11) & (S - 1);
  const int b = (int)(idx >> 22);
  out[idx] = in[(((long)(b * H + h) * S + s) << 7) + d];
}

// G = sign/pow(leaky_relu(A_LM)); reads Gb f32 [bh,d,f], writes bf16 G^T [bh,f,d]
__global__ __launch_bounds__(256) void plga_g_t(const float* __restrict__ a,
                                                const float* __restrict__ pw,
                                                bf16* __restrict__ gt)
{
  const long idx = (long)blockIdx.x * 256 + threadIdx.x;
  const int f = idx & 127;
  const int dd = (idx >> 7) & 127;
  const int bh = (int)(idx >> 14);
  const int h = bh & (H - 1);
  float x = a[idx];
  x = x > 0.f ? x : NEG_SLOPE * x;
  const float gq = powf(fabsf(x) + EPSV, pw[h]);
  const float gv = x > 0.f ? gq : (x < 0.f ? -gq : 0.f);
  gt[((long)bh << 14) + f * 128 + dd] = __float2bfloat16(gv);
}

// causal softmax: f32 scores chunk [32*128][S] -> bf16 probs over [0,Kv)
__global__ __launch_bounds__(256) void softmax_causal_b(
    const float* __restrict__ sc, bf16* __restrict__ pb, int chunk0)
{
  const int r = blockIdx.x;
  const int sl = r & 127;
  const int valid = chunk0 + sl + 1;
  const int Kv = chunk0 + 128;
  const float* row = sc + (long)r * S;
  bf16* prow = pb + (long)r * S;
  const int t = threadIdx.x;
  __shared__ float red[256];

  float mx = -1e30f;
  for (int i = t; i < valid; i += 256) mx = fmaxf(mx, row[i]);
  red[t] = mx; __syncthreads();
  for (int o = 128; o > 0; o >>= 1) { if (t < o) red[t] = fmaxf(red[t], red[t + o]); __syncthreads(); }
  mx = red[0]; __syncthreads();

  float sum = 0.f;
  for (int i = t; i < valid; i += 256) sum += __expf(row[i] - mx);
  red[t] = sum; __syncthreads();
  for (int o = 128; o > 0; o >>= 1) { if (t < o) red[t] += red[t + o]; __syncthreads(); }
  const float inv = 1.f / red[0];

  for (int i = t; i < valid; i += 256) prow[i] = __float2bfloat16(__expf(row[i] - mx) * inv);
  for (int i = valid + t; i < Kv; i += 256) prow[i] = __float2bfloat16(0.f);
}

}  // namespace

extern "C" void kernel_launch(void* const* d_in, const int* in_sizes, int n_in,
                              void* d_out, int out_size, void* d_ws, size_t ws_size,
                              hipStream_t stream)
{
  const float* q_in    = (const float*)d_in[0];
  const float* k_in    = (const float*)d_in[1];
  const float* v_in    = (const float*)d_in[2];
  const float* wq_w    = (const float*)d_in[4];
  const float* wq_b    = (const float*)d_in[5];
  const float* wk_w    = (const float*)d_in[6];
  const float* wk_b    = (const float*)d_in[7];
  const float* wv_w    = (const float*)d_in[8];
  const float* wv_b    = (const float*)d_in[9];
  const float* dense_w = (const float*)d_in[10];
  const float* dense_b = (const float*)d_in[11];
  const float* ln1_g   = (const float*)d_in[12];
  const float* ln1_b   = (const float*)d_in[13];
  const float* res_w1  = (const float*)d_in[14];
  const float* res_b1  = (const float*)d_in[15];
  const float* res_w2  = (const float*)d_in[16];
  const float* res_b2  = (const float*)d_in[17];
  const float* res_w3  = (const float*)d_in[18];
  const float* res_b3  = (const float*)d_in[19];
  const float* res_lng = (const float*)d_in[20];
  const float* res_lnb = (const float*)d_in[21];
  const float* plga_W  = (const float*)d_in[22];
  const float* plga_b  = (const float*)d_in[23];
  const float* plga_pw = (const float*)d_in[24];
  float* out = (float*)d_out;

  const long NBS = (long)B * S * D;            // 8388608
  const long NA  = (long)B * H * DHd * DHd;    // 524288
  const long DDw = (long)D * D;                // 4194304
  const long NW  = (long)NRES * NDENSE * A_DFF * DHd;  // 524288

  float* ws = (float*)d_ws;
  float* qp = ws;               // q proj f32; later probs bf16
  float* kp = ws + NBS;         // k proj f32; later Hnbh/Hnb bf16
  float* vp = ws + 2 * NBS;     // v proj f32; later Abuf/Gb f32, then scores
  float* qhslot = ws + 3 * NBS; // qTb bf16 (1st half), GTb bf16 (2nd half)
  float* Abuf = vp;
  float* Gb   = vp + NA;
  float* scoresf = vp;

  bf16* bbase = (bf16*)(ws + 4 * NBS);
  bf16* qb  = bbase;            // q_in bf16; later qhb (rope'd heads)
  bf16* kb  = bbase + NBS;      // k_in bf16; later khb
  bf16* vb  = bbase + 2 * NBS;  // v_in bf16; later vT
  bf16* wqb = bbase + 3 * NBS;  // later qgb
  bf16* wkb = wqb + DDw;
  bf16* wvb = wqb + 2 * DDw;    // later wdb
  bf16* qhb = qb;
  bf16* khb = kb;
  bf16* vT  = vb;
  bf16* qgb = wqb;
  bf16* wdb = wvb;
  bf16* qTb = (bf16*)qhslot;
  bf16* GTb = (bf16*)qhslot + NBS;
  bf16* probsb = (bf16*)qp;
  bf16* Hnbh = (bf16*)kp;
  bf16* Hnb  = Hnbh + NBS;
  float* w1t = (float*)(bbase + 3 * NBS + 3 * DDw);  // [16][128][256]
  float* w2t = w1t + NW;
  float* w3t = w2t + NW;

  // ---- convert inputs + weights to bf16; transpose stack weights
  f2b<<<(int)(NBS / 1024), 256, 0, stream>>>(q_in, qb);
  f2b<<<(int)(NBS / 1024), 256, 0, stream>>>(k_in, kb);
  f2b<<<(int)(NBS / 1024), 256, 0, stream>>>(v_in, vb);
  f2b<<<(int)(DDw / 1024), 256, 0, stream>>>(wq_w, wqb);
  f2b<<<(int)(DDw / 1024), 256, 0, stream>>>(wk_w, wkb);
  f2b<<<(int)(DDw / 1024), 256, 0, stream>>>(wv_w, wvb);
  tr_w<<<(int)(NW / 256), 256, 0, stream>>>(res_w1, w1t, A_DFF, DHd);
  tr_w<<<(int)(NW / 256), 256, 0, stream>>>(res_w2, w2t, A_DFF, DHd);
  tr_w<<<(int)(NW / 256), 256, 0, stream>>>(res_w3, w3t, DHd, A_DFF);

  // ---- QKV projections (bf16 MFMA)
  gemm_bt_mfma<false, true><<<dim3(32, 16, 1), 256, 0, stream>>>(
      qb, wqb, wq_b, qp, D, D, D, D, 0, 0, 0, 1.f);
  gemm_bt_mfma<false, true><<<dim3(32, 16, 1), 256, 0, stream>>>(
      kb, wkb, wk_b, kp, D, D, D, D, 0, 0, 0, 1.f);
  gemm_bt_mfma<false, true><<<dim3(32, 16, 1), 256, 0, stream>>>(
      vb, wvb, wv_b, vp, D, D, D, D, 0, 0, 0, 1.f);

  f2b<<<(int)(DDw / 1024), 256, 0, stream>>>(dense_w, wdb);

  // ---- RoPE + head transposes
  rope_tr2<<<16384, 256, 0, stream>>>(qp, qhb);
  rope_tr2<<<16384, 256, 0, stream>>>(kp, khb);
  tr_v_b<<<32768, 256, 0, stream>>>(vp, vT);
  tr_qT<<<dim3(32, 2, 32), 256, 0, stream>>>(qhb, qTb);

  // ---- metric A = q^T q per (b,h): split-K MFMA + f32 atomics
  hipMemsetAsync(Abuf, 0, NA * sizeof(float), stream);
  qtq_splitk<<<dim3(KSPLIT, 1, 32), 256, 0, stream>>>(qTb, Abuf);
  ln_row<<<B * H * DHd, 64, 0, stream>>>(Abuf, ln1_g, ln1_b, Abuf);

  // ---- fused residual SwiGLU stack (fp32, one dispatch, 512 wgs)
  res_stack<<<512, 256, 0, stream>>>(Abuf, w1t, res_b1, w2t, res_b2,
                                     w3t, res_b3, res_lng, res_lnb);

  // ---- plga: A_LM = W[h] @ A[b,h] + b[h] (fp32), then G^T bf16
  for (int b2 = 0; b2 < B; ++b2)
    gemm64<0, 0><<<dim3(2, 2, 16), 256, 0, stream>>>(plga_W,
        Abuf + (long)b2 * H * DHd * DHd, plga_b, Gb + (long)b2 * H * DHd * DHd,
        DHd, DHd, DHd, DHd, DHd,
        (long)DHd * DHd, (long)DHd * DHd, (long)DHd * DHd, DHd, 1.f);
  plga_g_t<<<(int)(NA / 256), 256, 0, stream>>>(Gb, plga_pw, GTb);

  // ---- qg = q @ G per (b,h)
  gemm_bt_mfma<true, false><<<dim3(16, 1, 32), 256, 0, stream>>>(
      qhb, GTb, nullptr, qgb, DHd, DHd, DHd, DHd,
      (long)S * DHd, (long)DHd * DHd, (long)S * DHd, 1.f);

  // ---- attention, chunks of 128 q rows; causal tile-skip
  for (int c = 0; c < S / 128; ++c) {
    const int Kv = (c + 1) * 128;
    gemm_bt_mfma<false, false><<<dim3(1, c + 1, 32), 256, 0, stream>>>(
        qgb + (long)c * 128 * DHd, khb, nullptr, scoresf,
        DHd, DHd, DHd, S, (long)S * DHd, (long)S * DHd, (long)128 * S, SCALE);
    softmax_causal_b<<<32 * 128, 256, 0, stream>>>(scoresf, probsb, c * 128);
    gemm_bt_mfma<true, false><<<dim3(1, 1, 32), 256, 0, stream>>>(
        probsb, vT, nullptr, Hnbh + (long)c * 128 * DHd,
        Kv, S, S, DHd, (long)128 * S, (long)DHd * S, (long)S * DHd, 1.f);
  }

  // ---- back to [B,S,D] and final dense (f32 out)
  untr_b<<<32768, 256, 0, stream>>>(Hnbh, Hnb);
  gemm_bt_mfma<false, true><<<dim3(32, 16, 1), 256, 0, stream>>>(
      Hnb, wdb, dense_b, out, D, D, D, D, 0, 0, 0, 1.f);
}

// Round 8
// 1127.230 us; speedup vs baseline: 5.3175x; 1.5423x over previous
//
#include <hip/hip_runtime.h>
#include <hip/hip_bf16.h>
#include <math.h>

namespace {

constexpr int B = 2, S = 2048, D = 2048, H = 16, DHd = 128, A_DFF = 256;
constexpr int NRES = 8, NDENSE = 2;
constexpr float EPSV = 1e-6f;
constexpr float NEG_SLOPE = 0.2f;
constexpr float SCALE = 0.08838834764831843f; // 1/sqrt(128)

constexpr int TS = 64, KT = 16;
constexpr int KSPLIT = 8;

using bf16 = __hip_bfloat16;
using short8 = __attribute__((ext_vector_type(8))) short;
using f32x4  = __attribute__((ext_vector_type(4))) float;

typedef const __attribute__((address_space(1))) unsigned int* gas_ptr;
typedef __attribute__((address_space(3))) unsigned int* las_ptr;

__device__ __forceinline__ void glds16(const void* g, void* l) {
  __builtin_amdgcn_global_load_lds((gas_ptr)g, (las_ptr)l, 16, 0, 0);
}

// ---------------------------------------------------------------------------
// bf16 MFMA GEMM: C[M,N] = scale * (A[M,K] @ Bt[N,K]^T) + bias
// 128x128 tile, BK=32, 256 threads (4 waves), m97 structure.
// ---------------------------------------------------------------------------
template<bool OUT_BF16, bool BIAS>
__global__ __launch_bounds__(256) void gemm_bt_mfma(
    const bf16* __restrict__ A, const bf16* __restrict__ Bt,
    const float* __restrict__ bias, void* __restrict__ Cv,
    int K, int lda, int ldb, int ldc,
    long sA, long sB, long sC, float scale)
{
  A  += (long)blockIdx.z * sA;
  Bt += (long)blockIdx.z * sB;

  __shared__ short As[128 * 32] __attribute__((aligned(16)));
  __shared__ short Bs[128 * 32] __attribute__((aligned(16)));

  const int t = threadIdx.x;
  const int wv = t >> 6, l = t & 63;
  const int m0 = blockIdx.x * 128, n0 = blockIdx.y * 128;

  const int sr = t >> 2, sc = (t & 3) * 8;
  short* ldsA0 = As + wv * 512;
  short* ldsA1 = As + 2048 + wv * 512;
  short* ldsB0 = Bs + wv * 512;
  short* ldsB1 = Bs + 2048 + wv * 512;

  const int wr = wv >> 1, wc = wv & 1;
  const int lr = l & 15, lk = (l >> 4) * 8;

  f32x4 acc[4][4] = {};

  for (int k0 = 0; k0 < K; k0 += 32) {
    __syncthreads();
    glds16(A  + (long)(m0 + sr)      * lda + k0 + sc, ldsA0);
    glds16(A  + (long)(m0 + 64 + sr) * lda + k0 + sc, ldsA1);
    glds16(Bt + (long)(n0 + sr)      * ldb + k0 + sc, ldsB0);
    glds16(Bt + (long)(n0 + 64 + sr) * ldb + k0 + sc, ldsB1);
    __syncthreads();

    short8 af[4], bf[4];
#pragma unroll
    for (int m = 0; m < 4; ++m)
      af[m] = *(const short8*)&As[(wr * 64 + m * 16 + lr) * 32 + lk];
#pragma unroll
    for (int n = 0; n < 4; ++n)
      bf[n] = *(const short8*)&Bs[(wc * 64 + n * 16 + lr) * 32 + lk];
#pragma unroll
    for (int m = 0; m < 4; ++m)
#pragma unroll
      for (int n = 0; n < 4; ++n)
        acc[m][n] = __builtin_amdgcn_mfma_f32_16x16x32_bf16(af[m], bf[n], acc[m][n], 0, 0, 0);
  }

  const int rb = m0 + wr * 64 + (l >> 4) * 4;
  const int cb = n0 + wc * 64 + (l & 15);
#pragma unroll
  for (int m = 0; m < 4; ++m)
#pragma unroll
    for (int n = 0; n < 4; ++n) {
      const int col = cb + n * 16;
      float bv = BIAS ? bias[col] : 0.f;
#pragma unroll
      for (int r = 0; r < 4; ++r) {
        const long off = (long)(rb + m * 16 + r) * ldc + col + blockIdx.z * sC;
        const float c = acc[m][n][r] * scale + bv;
        if (OUT_BF16) ((bf16*)Cv)[off] = __float2bfloat16(c);
        else          ((float*)Cv)[off] = c;
      }
    }
}

// ---------------------------------------------------------------------------
// A = qT @ qT^T per (b,h), split-K, f32 atomicAdd. Output pre-zeroed.
// ---------------------------------------------------------------------------
__global__ __launch_bounds__(256) void qtq_splitk(
    const bf16* __restrict__ qT, float* __restrict__ Aout)
{
  const int ks = blockIdx.x;
  const long bh = blockIdx.z;
  const bf16* Ab = qT + (bh << 7) * S;
  float* Cf = Aout + (bh << 14);

  __shared__ short As[128 * 32] __attribute__((aligned(16)));

  const int t = threadIdx.x;
  const int wv = t >> 6, l = t & 63;
  const int sr = t >> 2, sc = (t & 3) * 8;
  short* ldsA0 = As + wv * 512;
  short* ldsA1 = As + 2048 + wv * 512;

  const int wr = wv >> 1, wc = wv & 1;
  const int lr = l & 15, lk = (l >> 4) * 8;

  f32x4 acc[4][4] = {};

  const int kbeg = ks * (S / KSPLIT), kend = kbeg + S / KSPLIT;
  for (int k0 = kbeg; k0 < kend; k0 += 32) {
    __syncthreads();
    glds16(Ab + (long)sr * S + k0 + sc, ldsA0);
    glds16(Ab + (long)(64 + sr) * S + k0 + sc, ldsA1);
    __syncthreads();

    short8 af[4], bf[4];
#pragma unroll
    for (int m = 0; m < 4; ++m)
      af[m] = *(const short8*)&As[(wr * 64 + m * 16 + lr) * 32 + lk];
#pragma unroll
    for (int n = 0; n < 4; ++n)
      bf[n] = *(const short8*)&As[(wc * 64 + n * 16 + lr) * 32 + lk];
#pragma unroll
    for (int m = 0; m < 4; ++m)
#pragma unroll
      for (int n = 0; n < 4; ++n)
        acc[m][n] = __builtin_amdgcn_mfma_f32_16x16x32_bf16(af[m], bf[n], acc[m][n], 0, 0, 0);
  }

  const int rb = wr * 64 + (l >> 4) * 4;
  const int cb = wc * 64 + (l & 15);
#pragma unroll
  for (int m = 0; m < 4; ++m)
#pragma unroll
    for (int n = 0; n < 4; ++n)
#pragma unroll
      for (int r = 0; r < 4; ++r)
        atomicAdd(&Cf[(long)(rb + m * 16 + r) * 128 + cb + n * 16], acc[m][n][r]);
}

// ---------------------------------------------------------------------------
// Fused causal flash attention.
// grid = (16 q-chunks, 1, 32 bh), 256 threads (4 waves).
// Q = qg [bh][S][128], K = kh [bh][S][128], V^T = vT [bh][128][S].
// Each wave owns 32 q rows (Q in regs); KV tiles of 64 staged in LDS with
// XOR swizzle (T2); P goes through per-wave swizzled LDS; online softmax.
// Output written directly to Hnb [B*S][H*128] bf16.
// ---------------------------------------------------------------------------
__global__ __launch_bounds__(256, 2) void flash_attn(
    const bf16* __restrict__ qg, const bf16* __restrict__ kh,
    const bf16* __restrict__ vT, bf16* __restrict__ Hnb)
{
  const int c  = blockIdx.x;
  const int bh = blockIdx.z;
  const int bq = bh >> 4, hq = bh & 15;
  const int q0 = c * 128;

  __shared__ short Kt[64 * 128] __attribute__((aligned(16)));   // [kv][dh]
  __shared__ short Vt[128 * 64] __attribute__((aligned(16)));   // [dh][kv]
  __shared__ short Pt[4][32 * 64] __attribute__((aligned(16))); // per-wave

  const int t = threadIdx.x;
  const int wv = t >> 6, l = t & 63;
  const int lr = l & 15, lq = l >> 4;
  const int wrow0 = wv * 32;

  const bf16* qgb = qg + (long)bh * S * 128;
  const bf16* khb = kh + (long)bh * S * 128;
  const bf16* vTb = vT + (long)bh * 128 * S;

  // staging coords (loop-invariant). K: 4 rows/wave/pass; V: 8 rows/wave/pass.
  const int krow = wv * 4 + lq;                       // + p*16
  const int kcol = (lr * 8) ^ ((krow & 7) << 3);      // swizzled short offset
  const int vrow = wv * 8 + (l >> 3);                 // + p*32
  const int vcol = ((l & 7) * 8) ^ ((vrow & 7) << 3);

  // Q fragments (held for whole block)
  short8 aq[2][4];
#pragma unroll
  for (int m = 0; m < 2; ++m)
#pragma unroll
    for (int ks = 0; ks < 4; ++ks)
      aq[m][ks] = *(const short8*)&qgb[(long)(q0 + wrow0 + m * 16 + lr) * 128 + ks * 32 + lq * 8];

  f32x4 oacc[2][8] = {};
  float mrow[2][4], lrow[2][4];
#pragma unroll
  for (int m = 0; m < 2; ++m)
#pragma unroll
    for (int r = 0; r < 4; ++r) { mrow[m][r] = -1e30f; lrow[m][r] = 0.f; }

  const int jmax = 2 * (c + 1);
  for (int j = 0; j < jmax; ++j) {
    const int kv0 = j * 64;
    __syncthreads();
#pragma unroll
    for (int p = 0; p < 4; ++p) {
      glds16(khb + (long)(kv0 + p * 16 + krow) * 128 + kcol, Kt + p * 2048 + wv * 512);
      glds16(vTb + (long)(p * 32 + vrow) * S + kv0 + vcol, Vt + p * 2048 + wv * 512);
    }
    __syncthreads();

    // ---- QK^T (rows: this wave's 32; cols: 64 kv)
    f32x4 sacc[2][4] = {};
#pragma unroll
    for (int ks = 0; ks < 4; ++ks) {
      short8 bf[4];
#pragma unroll
      for (int n = 0; n < 4; ++n) {
        const int row = n * 16 + lr;
        bf[n] = *(const short8*)((const char*)Kt + row * 256 +
                 (((ks * 32 + lq * 8) * 2) ^ ((row & 7) << 4)));
      }
#pragma unroll
      for (int m = 0; m < 2; ++m)
#pragma unroll
        for (int n = 0; n < 4; ++n)
          sacc[m][n] = __builtin_amdgcn_mfma_f32_16x16x32_bf16(aq[m][ks], bf[n], sacc[m][n], 0, 0, 0);
    }

    // ---- mask + online softmax + P->LDS (bf16, swizzled)
#pragma unroll
    for (int m = 0; m < 2; ++m)
#pragma unroll
    for (int rr = 0; rr < 4; ++rr) {
      const int prow = m * 16 + lq * 4 + rr;          // wave-local row 0..31
      const int row_g = q0 + wrow0 + prow;
      float s[4];
      float tm = -1e30f;
#pragma unroll
      for (int n = 0; n < 4; ++n) {
        float v = sacc[m][n][rr] * SCALE;
        if (kv0 + n * 16 + lr > row_g) v = -1e30f;
        s[n] = v; tm = fmaxf(tm, v);
      }
      tm = fmaxf(tm, __shfl_xor(tm, 1));
      tm = fmaxf(tm, __shfl_xor(tm, 2));
      tm = fmaxf(tm, __shfl_xor(tm, 4));
      tm = fmaxf(tm, __shfl_xor(tm, 8));
      const float mo = mrow[m][rr];
      const float mn = fmaxf(mo, tm);
      const float scl = __expf(mo - mn);
      float ls = 0.f;
#pragma unroll
      for (int n = 0; n < 4; ++n) {
        const float p_ = __expf(s[n] - mn);
        ls += p_;
        const int col = n * 16 + lr;
        *(bf16*)((char*)Pt[wv] + prow * 128 + ((col * 2) ^ ((prow & 7) << 4))) =
            __float2bfloat16(p_);
      }
      ls += __shfl_xor(ls, 1); ls += __shfl_xor(ls, 2);
      ls += __shfl_xor(ls, 4); ls += __shfl_xor(ls, 8);
      lrow[m][rr] = lrow[m][rr] * scl + ls;
      mrow[m][rr] = mn;
#pragma unroll
      for (int n2 = 0; n2 < 8; ++n2) oacc[m][n2][rr] *= scl;
    }

    // ---- PV (same-wave P; LDS pipe is in-order, compiler inserts lgkmcnt)
#pragma unroll
    for (int ks = 0; ks < 2; ++ks) {
      short8 pa[2], vb[8];
#pragma unroll
      for (int m = 0; m < 2; ++m) {
        const int row = m * 16 + lr;
        pa[m] = *(const short8*)((const char*)Pt[wv] + row * 128 +
                 (((ks * 32 + lq * 8) * 2) ^ ((row & 7) << 4)));
      }
#pragma unroll
      for (int n2 = 0; n2 < 8; ++n2) {
        const int row = n2 * 16 + lr;
        vb[n2] = *(const short8*)((const char*)Vt + row * 128 +
                  (((ks * 32 + lq * 8) * 2) ^ ((row & 7) << 4)));
      }
#pragma unroll
      for (int m = 0; m < 2; ++m)
#pragma unroll
        for (int n2 = 0; n2 < 8; ++n2)
          oacc[m][n2] = __builtin_amdgcn_mfma_f32_16x16x32_bf16(pa[m], vb[n2], oacc[m][n2], 0, 0, 0);
    }
  }

  // ---- epilogue: O/l, write [B,S,H*DH] directly
#pragma unroll
  for (int m = 0; m < 2; ++m)
#pragma unroll
  for (int rr = 0; rr < 4; ++rr) {
    const int row_l = wrow0 + m * 16 + lq * 4 + rr;
    const float inv = 1.f / lrow[m][rr];
    bf16* orow = Hnb + ((long)(bq * S + q0 + row_l)) * D + hq * 128;
#pragma unroll
    for (int n2 = 0; n2 < 8; ++n2)
      orow[n2 * 16 + lr] = __float2bfloat16(oacc[m][n2][rr] * inv);
  }
}

// ---------------------------------------------------------------------------
// fp32 GEMM (only used for plga). MODE 0: C=A@B.
// ---------------------------------------------------------------------------
template<int MODE, int ACT>
__global__ __launch_bounds__(256) void gemm64(
    const float* __restrict__ A, const float* __restrict__ Bm,
    const float* __restrict__ bias, float* __restrict__ C,
    int M, int N, int K, int lda, int ldb,
    long sA, long sB, long sC, long sBias, float scale)
{
  A  += (long)blockIdx.z * sA;
  Bm += (long)blockIdx.z * sB;
  C  += (long)blockIdx.z * sC;
  if (bias) bias += (long)blockIdx.z * sBias;

  __shared__ float As[KT][TS + 4];
  __shared__ float Bs[KT][TS + 4];

  const int t = threadIdx.x;
  const int m0 = blockIdx.x * TS, n0 = blockIdx.y * TS;
  const int tm = (t & 15) * 4;
  const int tn = (t >> 4) * 4;

  float acc[4][4] = {};

  for (int k0 = 0; k0 < K; k0 += KT) {
    if (MODE == 2) {
      const int kk = t >> 6, mm = t & 63;
#pragma unroll
      for (int p = 0; p < 4; ++p)
        As[kk + p * 4][mm] = A[(long)(k0 + kk + p * 4) * lda + m0 + mm];
    } else {
      const int kk = t & 15, mm = t >> 4;
#pragma unroll
      for (int p = 0; p < 4; ++p)
        As[kk][mm + p * 16] = A[(long)(m0 + mm + p * 16) * lda + k0 + kk];
    }
    if (MODE == 1) {
      const int kk = t & 15, nn = t >> 4;
#pragma unroll
      for (int p = 0; p < 4; ++p)
        Bs[kk][nn + p * 16] = Bm[(long)(n0 + nn + p * 16) * ldb + k0 + kk];
    } else {
      const int kk = t >> 6, nn = t & 63;
#pragma unroll
      for (int p = 0; p < 4; ++p)
        Bs[kk + p * 4][nn] = Bm[(long)(k0 + kk + p * 4) * ldb + n0 + nn];
    }
    __syncthreads();

#pragma unroll
    for (int kk = 0; kk < KT; ++kk) {
      float4 av = *(const float4*)&As[kk][tm];
      float4 bv = *(const float4*)&Bs[kk][tn];
      float a[4] = {av.x, av.y, av.z, av.w};
      float b[4] = {bv.x, bv.y, bv.z, bv.w};
#pragma unroll
      for (int i = 0; i < 4; ++i)
#pragma unroll
        for (int j = 0; j < 4; ++j)
          acc[i][j] += a[i] * b[j];
    }
    __syncthreads();
  }

#pragma unroll
  for (int i = 0; i < 4; ++i) {
    const int m = m0 + tm + i;
#pragma unroll
    for (int j = 0; j < 4; ++j) {
      const int n = n0 + tn + j;
      float c = acc[i][j] * scale;
      if (bias) c += bias[n];
      if (ACT == 1) c = c / (1.f + __expf(-c));
      C[(long)m * N + n] = c;
    }
  }
}

// ---------------------------------------------------------------------------
// Fused residual SwiGLU stack (RROWS=8, 512 wgs, 2-stage prefetch).
// ---------------------------------------------------------------------------
constexpr int RROWS = 8;
__global__ __launch_bounds__(256, 2) void res_stack(
    float* __restrict__ Abuf,
    const float* __restrict__ w1t, const float* __restrict__ b1,
    const float* __restrict__ w2t, const float* __restrict__ b2,
    const float* __restrict__ w3t, const float* __restrict__ b3,
    const float* __restrict__ lng, const float* __restrict__ lnb)
{
  const int bh = blockIdx.x >> 4;
  const int r0 = (blockIdx.x & 15) * RROWS;
  float* Ag = Abuf + ((long)bh << 14) + (long)r0 * 128;

  __shared__ float Ar[RROWS][128];
  __shared__ float Res[RROWS][128];
  __shared__ float g[RROWS][256];

  const int t = threadIdx.x;
  for (int x = t; x < RROWS * 128; x += 256)
    Ar[x >> 7][x & 127] = Ag[(long)(x >> 7) * 128 + (x & 127)];
  __syncthreads();

  for (int l = 0; l < NRES; ++l) {
    for (int x = t; x < RROWS * 128; x += 256)
      Res[x >> 7][x & 127] = Ar[x >> 7][x & 127];
    __syncthreads();

    for (int n = 0; n < NDENSE; ++n) {
      const long wo = (long)(l * NDENSE + n);
      const float* W1 = w1t + wo * DHd * A_DFF;
      const float* W2 = w2t + wo * DHd * A_DFF;
      const float* W3 = w3t + wo * A_DFF * DHd;
      const float bb1 = b1[wo * A_DFF + t];
      const float bb2 = b2[wo * A_DFF + t];

      float a1[RROWS] = {}, a2[RROWS] = {};
      float w1a[4], w2a[4], w1b[4], w2b[4];
#pragma unroll
      for (int k = 0; k < 4; ++k) {
        w1a[k] = W1[(long)k * A_DFF + t];
        w2a[k] = W2[(long)k * A_DFF + t];
      }
      for (int jb = 0; jb < 32; jb += 2) {
#pragma unroll
        for (int k = 0; k < 4; ++k) {
          w1b[k] = W1[(long)((jb + 1) * 4 + k) * A_DFF + t];
          w2b[k] = W2[(long)((jb + 1) * 4 + k) * A_DFF + t];
        }
#pragma unroll
        for (int i = 0; i < RROWS; ++i) {
          const float4 av = *(const float4*)&Ar[i][jb * 4];
          a1[i] += av.x * w1a[0] + av.y * w1a[1] + av.z * w1a[2] + av.w * w1a[3];
          a2[i] += av.x * w2a[0] + av.y * w2a[1] + av.z * w2a[2] + av.w * w2a[3];
        }
        if (jb + 2 < 32) {
#pragma unroll
          for (int k = 0; k < 4; ++k) {
            w1a[k] = W1[(long)((jb + 2) * 4 + k) * A_DFF + t];
            w2a[k] = W2[(long)((jb + 2) * 4 + k) * A_DFF + t];
          }
        }
#pragma unroll
        for (int i = 0; i < RROWS; ++i) {
          const float4 av = *(const float4*)&Ar[i][jb * 4 + 4];
          a1[i] += av.x * w1b[0] + av.y * w1b[1] + av.z * w1b[2] + av.w * w1b[3];
          a2[i] += av.x * w2b[0] + av.y * w2b[1] + av.z * w2b[2] + av.w * w2b[3];
        }
      }
#pragma unroll
      for (int i = 0; i < RROWS; ++i) {
        float x1 = a1[i] + bb1;
        x1 = x1 / (1.f + __expf(-x1));
        g[i][t] = x1 * (a2[i] + bb2);
      }
      __syncthreads();

      const int p = t & 127, ih = t >> 7;
      const float bb3 = b3[wo * DHd + p];
      float a3[4] = {};
      float w3a[4], w3b[4];
#pragma unroll
      for (int k = 0; k < 4; ++k) w3a[k] = W3[(long)k * DHd + p];
      for (int ob = 0; ob < 64; ob += 2) {
#pragma unroll
        for (int k = 0; k < 4; ++k)
          w3b[k] = W3[(long)((ob + 1) * 4 + k) * DHd + p];
#pragma unroll
        for (int i = 0; i < 4; ++i) {
          const float4 gv = *(const float4*)&g[ih * 4 + i][ob * 4];
          a3[i] += gv.x * w3a[0] + gv.y * w3a[1] + gv.z * w3a[2] + gv.w * w3a[3];
        }
        if (ob + 2 < 64) {
#pragma unroll
          for (int k = 0; k < 4; ++k)
            w3a[k] = W3[(long)((ob + 2) * 4 + k) * DHd + p];
        }
#pragma unroll
        for (int i = 0; i < 4; ++i) {
          const float4 gv = *(const float4*)&g[ih * 4 + i][ob * 4 + 4];
          a3[i] += gv.x * w3b[0] + gv.y * w3b[1] + gv.z * w3b[2] + gv.w * w3b[3];
        }
      }
      __syncthreads();
#pragma unroll
      for (int i = 0; i < 4; ++i) Ar[ih * 4 + i][p] = a3[i] + bb3;
      __syncthreads();
    }

    {
      const int wv_ = t >> 6, l_ = t & 63;
#pragma unroll
      for (int i = wv_ * 2; i < wv_ * 2 + 2; ++i) {
        float v0 = Ar[i][l_] + Res[i][l_];
        float v1 = Ar[i][l_ + 64] + Res[i][l_ + 64];
        float s = v0 + v1;
#pragma unroll
        for (int o = 32; o > 0; o >>= 1) s += __shfl_down(s, o);
        const float mu = __shfl(s, 0) * (1.f / 128.f);
        const float d0 = v0 - mu, d1 = v1 - mu;
        float vs = d0 * d0 + d1 * d1;
#pragma unroll
        for (int o = 32; o > 0; o >>= 1) vs += __shfl_down(vs, o);
        const float rstd = rsqrtf(__shfl(vs, 0) * (1.f / 128.f) + EPSV);
        Ar[i][l_]      = d0 * rstd * lng[l * 128 + l_] + lnb[l * 128 + l_];
        Ar[i][l_ + 64] = d1 * rstd * lng[l * 128 + l_ + 64] + lnb[l * 128 + l_ + 64];
      }
    }
    __syncthreads();
  }

  for (int x = t; x < RROWS * 128; x += 256)
    Ag[(long)(x >> 7) * 128 + (x & 127)] = Ar[x >> 7][x & 127];
}

// transpose last two dims: in [L][R][C] -> out [L][C][R]
__global__ __launch_bounds__(256) void tr_w(const float* __restrict__ in,
                                            float* __restrict__ out, int R, int C)
{
  const long idx = (long)blockIdx.x * 256 + threadIdx.x;
  const int r = (int)(idx % R);
  const long tmp = idx / R;
  const int c = (int)(tmp % C);
  const long l = tmp / C;
  out[idx] = in[(l * R + r) * C + c];
}

// f32 -> bf16 convert, 4 elems/thread
__global__ __launch_bounds__(256) void f2b(const float* __restrict__ in,
                                           bf16* __restrict__ out)
{
  const long i = (long)blockIdx.x * 256 + threadIdx.x;
  const float4 v = ((const float4*)in)[i];
  bf16* o = out + i * 4;
  o[0] = __float2bfloat16(v.x); o[1] = __float2bfloat16(v.y);
  o[2] = __float2bfloat16(v.z); o[3] = __float2bfloat16(v.w);
}

// LayerNorm rows of 128 (for ln1), in-place safe.
__global__ __launch_bounds__(64) void ln_row(
    const float* __restrict__ in, const float* __restrict__ g,
    const float* __restrict__ b, float* __restrict__ out)
{
  const long r = blockIdx.x;
  const int t = threadIdx.x;
  float v0 = in[r * 128 + t], v1 = in[r * 128 + t + 64];
  float s = v0 + v1;
#pragma unroll
  for (int o = 32; o > 0; o >>= 1) s += __shfl_down(s, o);
  const float mu = __shfl(s, 0) * (1.f / 128.f);
  const float d0 = v0 - mu, d1 = v1 - mu;
  float vs = d0 * d0 + d1 * d1;
#pragma unroll
  for (int o = 32; o > 0; o >>= 1) vs += __shfl_down(vs, o);
  const float rstd = rsqrtf(__shfl(vs, 0) * (1.f / 128.f) + EPSV);
  out[r * 128 + t]      = d0 * rstd * g[t] + b[t];
  out[r * 128 + t + 64] = d1 * rstd * g[t + 64] + b[t + 64];
}

// [B,S,H,DH] f32 -> [B,H,S,DH] bf16 with RoPE.
__global__ __launch_bounds__(256) void rope_tr2(const float* __restrict__ in,
                                                bf16* __restrict__ outb)
{
  const long idx = (long)blockIdx.x * 256 + threadIdx.x;
  const int p = idx & 63;
  const int h = (idx >> 6) & (H - 1);
  const int s = (idx >> 10) & (S - 1);
  const int b = (int)(idx >> 21);
  const float theta = powf(10000.f, -(float)p * (1.f / 64.f));
  float sn, cs;
  sincosf((float)s * theta, &sn, &cs);
  const long src = (((long)(b * S + s) * H + h) << 7) + 2 * p;
  const float x1 = in[src], x2 = in[src + 1];
  const long dst = (((long)(b * H + h) * S + s) << 7) + 2 * p;
  outb[dst]     = __float2bfloat16(x1 * cs - x2 * sn);
  outb[dst + 1] = __float2bfloat16(x2 * cs + x1 * sn);
}

// bf16 tiled transpose: [BH][S][128] -> [BH][128][S]
__global__ __launch_bounds__(256) void tr_qT(const bf16* __restrict__ in,
                                             bf16* __restrict__ outT)
{
  __shared__ unsigned short tile[64][68];
  const int t = threadIdx.x;
  const int s0 = blockIdx.x * 64, d0 = blockIdx.y * 64;
  const long bh = blockIdx.z;
  const unsigned short* ip = (const unsigned short*)in + (bh * S + s0) * 128 + d0;
  unsigned short* op = (unsigned short*)outT + (bh * 128 + d0) * S + s0;
  const int r = t >> 4, c = (t & 15) * 4;
#pragma unroll
  for (int p = 0; p < 4; ++p) {
    const ushort4 v = *(const ushort4*)&ip[(long)(r + p * 16) * 128 + c];
    tile[r + p * 16][c]     = v.x;
    tile[r + p * 16][c + 1] = v.y;
    tile[r + p * 16][c + 2] = v.z;
    tile[r + p * 16][c + 3] = v.w;
  }
  __syncthreads();
#pragma unroll
  for (int p = 0; p < 4; ++p) {
    ushort4 w;
    w.x = tile[c][r + p * 16];
    w.y = tile[c + 1][r + p * 16];
    w.z = tile[c + 2][r + p * 16];
    w.w = tile[c + 3][r + p * 16];
    *(ushort4*)&op[(long)(r + p * 16) * S + c] = w;
  }
}

// [B,S,H,DH] f32 -> vT bf16 [B,H,DH,S]
__global__ __launch_bounds__(256) void tr_v_b(const float* __restrict__ in,
                                              bf16* __restrict__ out)
{
  const long idx = (long)blockIdx.x * 256 + threadIdx.x;
  const int s = idx & (S - 1);
  const int dh = (idx >> 11) & 127;
  const int h = (idx >> 18) & (H - 1);
  const int b = (int)(idx >> 22);
  out[idx] = __float2bfloat16(in[(((long)(b * S + s) * H + h) << 7) + dh]);
}

// G = sign/pow(leaky_relu(A_LM)); f32 [bh,d,f] -> bf16 G^T [bh,f,d]
__global__ __launch_bounds__(256) void plga_g_t(const float* __restrict__ a,
                                                const float* __restrict__ pw,
                                                bf16* __restrict__ gt)
{
  const long idx = (long)blockIdx.x * 256 + threadIdx.x;
  const int f = idx & 127;
  const int dd = (idx >> 7) & 127;
  const int bh = (int)(idx >> 14);
  const int h = bh & (H - 1);
  float x = a[idx];
  x = x > 0.f ? x : NEG_SLOPE * x;
  const float gq = powf(fabsf(x) + EPSV, pw[h]);
  const float gv = x > 0.f ? gq : (x < 0.f ? -gq : 0.f);
  gt[((long)bh << 14) + f * 128 + dd] = __float2bfloat16(gv);
}

}  // namespace

extern "C" void kernel_launch(void* const* d_in, const int* in_sizes, int n_in,
                              void* d_out, int out_size, void* d_ws, size_t ws_size,
                              hipStream_t stream)
{
  const float* q_in    = (const float*)d_in[0];
  const float* k_in    = (const float*)d_in[1];
  const float* v_in    = (const float*)d_in[2];
  const float* wq_w    = (const float*)d_in[4];
  const float* wq_b    = (const float*)d_in[5];
  const float* wk_w    = (const float*)d_in[6];
  const float* wk_b    = (const float*)d_in[7];
  const float* wv_w    = (const float*)d_in[8];
  const float* wv_b    = (const float*)d_in[9];
  const float* dense_w = (const float*)d_in[10];
  const float* dense_b = (const float*)d_in[11];
  const float* ln1_g   = (const float*)d_in[12];
  const float* ln1_b   = (const float*)d_in[13];
  const float* res_w1  = (const float*)d_in[14];
  const float* res_b1  = (const float*)d_in[15];
  const float* res_w2  = (const float*)d_in[16];
  const float* res_b2  = (const float*)d_in[17];
  const float* res_w3  = (const float*)d_in[18];
  const float* res_b3  = (const float*)d_in[19];
  const float* res_lng = (const float*)d_in[20];
  const float* res_lnb = (const float*)d_in[21];
  const float* plga_W  = (const float*)d_in[22];
  const float* plga_b  = (const float*)d_in[23];
  const float* plga_pw = (const float*)d_in[24];
  float* out = (float*)d_out;

  const long NBS = (long)B * S * D;            // 8388608
  const long NA  = (long)B * H * DHd * DHd;    // 524288
  const long DDw = (long)D * D;                // 4194304
  const long NW  = (long)NRES * NDENSE * A_DFF * DHd;  // 524288

  float* ws = (float*)d_ws;
  float* qp = ws;               // q proj f32
  float* kp = ws + NBS;         // k proj f32; later Hnb bf16
  float* vp = ws + 2 * NBS;     // v proj f32; later Abuf/Gb f32
  float* qhslot = ws + 3 * NBS; // qTb bf16 (1st half), GTb bf16 (2nd half)
  float* Abuf = vp;
  float* Gb   = vp + NA;

  bf16* bbase = (bf16*)(ws + 4 * NBS);
  bf16* qb  = bbase;            // q_in bf16; later qhb
  bf16* kb  = bbase + NBS;      // k_in bf16; later khb
  bf16* vb  = bbase + 2 * NBS;  // v_in bf16; later vT
  bf16* wqb = bbase + 3 * NBS;  // later qgb
  bf16* wkb = wqb + DDw;
  bf16* wvb = wqb + 2 * DDw;    // later wdb
  bf16* qhb = qb;
  bf16* khb = kb;
  bf16* vT  = vb;
  bf16* qgb = wqb;
  bf16* wdb = wvb;
  bf16* qTb = (bf16*)qhslot;
  bf16* GTb = (bf16*)qhslot + NBS;
  bf16* Hnb = (bf16*)kp;
  float* w1t = (float*)(bbase + 3 * NBS + 3 * DDw);
  float* w2t = w1t + NW;
  float* w3t = w2t + NW;

  // ---- convert inputs + weights to bf16; transpose stack weights
  f2b<<<(int)(NBS / 1024), 256, 0, stream>>>(q_in, qb);
  f2b<<<(int)(NBS / 1024), 256, 0, stream>>>(k_in, kb);
  f2b<<<(int)(NBS / 1024), 256, 0, stream>>>(v_in, vb);
  f2b<<<(int)(DDw / 1024), 256, 0, stream>>>(wq_w, wqb);
  f2b<<<(int)(DDw / 1024), 256, 0, stream>>>(wk_w, wkb);
  f2b<<<(int)(DDw / 1024), 256, 0, stream>>>(wv_w, wvb);
  tr_w<<<(int)(NW / 256), 256, 0, stream>>>(res_w1, w1t, A_DFF, DHd);
  tr_w<<<(int)(NW / 256), 256, 0, stream>>>(res_w2, w2t, A_DFF, DHd);
  tr_w<<<(int)(NW / 256), 256, 0, stream>>>(res_w3, w3t, DHd, A_DFF);

  // ---- QKV projections (bf16 MFMA)
  gemm_bt_mfma<false, true><<<dim3(32, 16, 1), 256, 0, stream>>>(
      qb, wqb, wq_b, qp, D, D, D, D, 0, 0, 0, 1.f);
  gemm_bt_mfma<false, true><<<dim3(32, 16, 1), 256, 0, stream>>>(
      kb, wkb, wk_b, kp, D, D, D, D, 0, 0, 0, 1.f);
  gemm_bt_mfma<false, true><<<dim3(32, 16, 1), 256, 0, stream>>>(
      vb, wvb, wv_b, vp, D, D, D, D, 0, 0, 0, 1.f);

  f2b<<<(int)(DDw / 1024), 256, 0, stream>>>(dense_w, wdb);

  // ---- RoPE + head transposes
  rope_tr2<<<16384, 256, 0, stream>>>(qp, qhb);
  rope_tr2<<<16384, 256, 0, stream>>>(kp, khb);
  tr_v_b<<<32768, 256, 0, stream>>>(vp, vT);
  tr_qT<<<dim3(32, 2, 32), 256, 0, stream>>>(qhb, qTb);

  // ---- metric A = q^T q per (b,h): split-K MFMA + f32 atomics
  hipMemsetAsync(Abuf, 0, NA * sizeof(float), stream);
  qtq_splitk<<<dim3(KSPLIT, 1, 32), 256, 0, stream>>>(qTb, Abuf);
  ln_row<<<B * H * DHd, 64, 0, stream>>>(Abuf, ln1_g, ln1_b, Abuf);

  // ---- fused residual SwiGLU stack
  res_stack<<<512, 256, 0, stream>>>(Abuf, w1t, res_b1, w2t, res_b2,
                                     w3t, res_b3, res_lng, res_lnb);

  // ---- plga (fp32), then G^T bf16
  for (int b2 = 0; b2 < B; ++b2)
    gemm64<0, 0><<<dim3(2, 2, 16), 256, 0, stream>>>(plga_W,
        Abuf + (long)b2 * H * DHd * DHd, plga_b, Gb + (long)b2 * H * DHd * DHd,
        DHd, DHd, DHd, DHd, DHd,
        (long)DHd * DHd, (long)DHd * DHd, (long)DHd * DHd, DHd, 1.f);
  plga_g_t<<<(int)(NA / 256), 256, 0, stream>>>(Gb, plga_pw, GTb);

  // ---- qg = q @ G per (b,h)
  gemm_bt_mfma<true, false><<<dim3(16, 1, 32), 256, 0, stream>>>(
      qhb, GTb, nullptr, qgb, DHd, DHd, DHd, DHd,
      (long)S * DHd, (long)DHd * DHd, (long)S * DHd, 1.f);

  // ---- fused causal flash attention (one dispatch)
  flash_attn<<<dim3(16, 1, 32), 256, 0, stream>>>(qgb, khb, vT, Hnb);

  // ---- final dense (f32 out)
  gemm_bt_mfma<false, true><<<dim3(32, 16, 1), 256, 0, stream>>>(
      Hnb, wdb, dense_b, out, D, D, D, D, 0, 0, 0, 1.f);
}

// Round 9
// 869.622 us; speedup vs baseline: 6.8927x; 1.2962x over previous
//
#include <hip/hip_runtime.h>
#include <hip/hip_bf16.h>
#include <math.h>

namespace {

constexpr int B = 2, S = 2048, D = 2048, H = 16, DHd = 128, A_DFF = 256;
constexpr int NRES = 8, NDENSE = 2;
constexpr float EPSV = 1e-6f;
constexpr float NEG_SLOPE = 0.2f;
constexpr float SCALE = 0.08838834764831843f; // 1/sqrt(128)

constexpr int TS = 64, KT = 16;
constexpr int KSPLIT = 8;

using bf16 = __hip_bfloat16;
using short8 = __attribute__((ext_vector_type(8))) short;
using f32x4  = __attribute__((ext_vector_type(4))) float;

typedef const __attribute__((address_space(1))) unsigned int* gas_ptr;
typedef __attribute__((address_space(3))) unsigned int* las_ptr;

__device__ __forceinline__ void glds16(const void* g, void* l) {
  __builtin_amdgcn_global_load_lds((gas_ptr)g, (las_ptr)l, 16, 0, 0);
}

// ---------------------------------------------------------------------------
// bf16 MFMA GEMM: C[M,N] = scale * (A[M,K] @ Bt[N,K]^T) + bias
// 128x128 tile, BK=32, 256 threads (4 waves), m97 structure.
// ---------------------------------------------------------------------------
template<bool OUT_BF16, bool BIAS>
__global__ __launch_bounds__(256) void gemm_bt_mfma(
    const bf16* __restrict__ A, const bf16* __restrict__ Bt,
    const float* __restrict__ bias, void* __restrict__ Cv,
    int K, int lda, int ldb, int ldc,
    long sA, long sB, long sC, float scale)
{
  A  += (long)blockIdx.z * sA;
  Bt += (long)blockIdx.z * sB;

  __shared__ short As[128 * 32] __attribute__((aligned(16)));
  __shared__ short Bs[128 * 32] __attribute__((aligned(16)));

  const int t = threadIdx.x;
  const int wv = t >> 6, l = t & 63;
  const int m0 = blockIdx.x * 128, n0 = blockIdx.y * 128;

  const int sr = t >> 2, sc = (t & 3) * 8;
  short* ldsA0 = As + wv * 512;
  short* ldsA1 = As + 2048 + wv * 512;
  short* ldsB0 = Bs + wv * 512;
  short* ldsB1 = Bs + 2048 + wv * 512;

  const int wr = wv >> 1, wc = wv & 1;
  const int lr = l & 15, lk = (l >> 4) * 8;

  f32x4 acc[4][4] = {};

  for (int k0 = 0; k0 < K; k0 += 32) {
    __syncthreads();
    glds16(A  + (long)(m0 + sr)      * lda + k0 + sc, ldsA0);
    glds16(A  + (long)(m0 + 64 + sr) * lda + k0 + sc, ldsA1);
    glds16(Bt + (long)(n0 + sr)      * ldb + k0 + sc, ldsB0);
    glds16(Bt + (long)(n0 + 64 + sr) * ldb + k0 + sc, ldsB1);
    __syncthreads();

    short8 af[4], bf[4];
#pragma unroll
    for (int m = 0; m < 4; ++m)
      af[m] = *(const short8*)&As[(wr * 64 + m * 16 + lr) * 32 + lk];
#pragma unroll
    for (int n = 0; n < 4; ++n)
      bf[n] = *(const short8*)&Bs[(wc * 64 + n * 16 + lr) * 32 + lk];
#pragma unroll
    for (int m = 0; m < 4; ++m)
#pragma unroll
      for (int n = 0; n < 4; ++n)
        acc[m][n] = __builtin_amdgcn_mfma_f32_16x16x32_bf16(af[m], bf[n], acc[m][n], 0, 0, 0);
  }

  const int rb = m0 + wr * 64 + (l >> 4) * 4;
  const int cb = n0 + wc * 64 + (l & 15);
#pragma unroll
  for (int m = 0; m < 4; ++m)
#pragma unroll
    for (int n = 0; n < 4; ++n) {
      const int col = cb + n * 16;
      float bv = BIAS ? bias[col] : 0.f;
#pragma unroll
      for (int r = 0; r < 4; ++r) {
        const long off = (long)(rb + m * 16 + r) * ldc + col + blockIdx.z * sC;
        const float c = acc[m][n][r] * scale + bv;
        if (OUT_BF16) ((bf16*)Cv)[off] = __float2bfloat16(c);
        else          ((float*)Cv)[off] = c;
      }
    }
}

// ---------------------------------------------------------------------------
// A = qT @ qT^T per (b,h), split-K, f32 atomicAdd. Output pre-zeroed.
// ---------------------------------------------------------------------------
__global__ __launch_bounds__(256) void qtq_splitk(
    const bf16* __restrict__ qT, float* __restrict__ Aout)
{
  const int ks = blockIdx.x;
  const long bh = blockIdx.z;
  const bf16* Ab = qT + (bh << 7) * S;
  float* Cf = Aout + (bh << 14);

  __shared__ short As[128 * 32] __attribute__((aligned(16)));

  const int t = threadIdx.x;
  const int wv = t >> 6, l = t & 63;
  const int sr = t >> 2, sc = (t & 3) * 8;
  short* ldsA0 = As + wv * 512;
  short* ldsA1 = As + 2048 + wv * 512;

  const int wr = wv >> 1, wc = wv & 1;
  const int lr = l & 15, lk = (l >> 4) * 8;

  f32x4 acc[4][4] = {};

  const int kbeg = ks * (S / KSPLIT), kend = kbeg + S / KSPLIT;
  for (int k0 = kbeg; k0 < kend; k0 += 32) {
    __syncthreads();
    glds16(Ab + (long)sr * S + k0 + sc, ldsA0);
    glds16(Ab + (long)(64 + sr) * S + k0 + sc, ldsA1);
    __syncthreads();

    short8 af[4], bf[4];
#pragma unroll
    for (int m = 0; m < 4; ++m)
      af[m] = *(const short8*)&As[(wr * 64 + m * 16 + lr) * 32 + lk];
#pragma unroll
    for (int n = 0; n < 4; ++n)
      bf[n] = *(const short8*)&As[(wc * 64 + n * 16 + lr) * 32 + lk];
#pragma unroll
    for (int m = 0; m < 4; ++m)
#pragma unroll
      for (int n = 0; n < 4; ++n)
        acc[m][n] = __builtin_amdgcn_mfma_f32_16x16x32_bf16(af[m], bf[n], acc[m][n], 0, 0, 0);
  }

  const int rb = wr * 64 + (l >> 4) * 4;
  const int cb = wc * 64 + (l & 15);
#pragma unroll
  for (int m = 0; m < 4; ++m)
#pragma unroll
    for (int n = 0; n < 4; ++n)
#pragma unroll
      for (int r = 0; r < 4; ++r)
        atomicAdd(&Cf[(long)(rb + m * 16 + r) * 128 + cb + n * 16], acc[m][n][r]);
}

// ---------------------------------------------------------------------------
// Fused causal flash attention (unchanged from round 5, verified round 8).
// ---------------------------------------------------------------------------
__global__ __launch_bounds__(256, 2) void flash_attn(
    const bf16* __restrict__ qg, const bf16* __restrict__ kh,
    const bf16* __restrict__ vT, bf16* __restrict__ Hnb)
{
  const int c  = blockIdx.x;
  const int bh = blockIdx.z;
  const int bq = bh >> 4, hq = bh & 15;
  const int q0 = c * 128;

  __shared__ short Kt[64 * 128] __attribute__((aligned(16)));   // [kv][dh]
  __shared__ short Vt[128 * 64] __attribute__((aligned(16)));   // [dh][kv]
  __shared__ short Pt[4][32 * 64] __attribute__((aligned(16))); // per-wave

  const int t = threadIdx.x;
  const int wv = t >> 6, l = t & 63;
  const int lr = l & 15, lq = l >> 4;
  const int wrow0 = wv * 32;

  const bf16* qgb = qg + (long)bh * S * 128;
  const bf16* khb = kh + (long)bh * S * 128;
  const bf16* vTb = vT + (long)bh * 128 * S;

  const int krow = wv * 4 + lq;
  const int kcol = (lr * 8) ^ ((krow & 7) << 3);
  const int vrow = wv * 8 + (l >> 3);
  const int vcol = ((l & 7) * 8) ^ ((vrow & 7) << 3);

  short8 aq[2][4];
#pragma unroll
  for (int m = 0; m < 2; ++m)
#pragma unroll
    for (int ks = 0; ks < 4; ++ks)
      aq[m][ks] = *(const short8*)&qgb[(long)(q0 + wrow0 + m * 16 + lr) * 128 + ks * 32 + lq * 8];

  f32x4 oacc[2][8] = {};
  float mrow[2][4], lrow[2][4];
#pragma unroll
  for (int m = 0; m < 2; ++m)
#pragma unroll
    for (int r = 0; r < 4; ++r) { mrow[m][r] = -1e30f; lrow[m][r] = 0.f; }

  const int jmax = 2 * (c + 1);
  for (int j = 0; j < jmax; ++j) {
    const int kv0 = j * 64;
    __syncthreads();
#pragma unroll
    for (int p = 0; p < 4; ++p) {
      glds16(khb + (long)(kv0 + p * 16 + krow) * 128 + kcol, Kt + p * 2048 + wv * 512);
      glds16(vTb + (long)(p * 32 + vrow) * S + kv0 + vcol, Vt + p * 2048 + wv * 512);
    }
    __syncthreads();

    f32x4 sacc[2][4] = {};
#pragma unroll
    for (int ks = 0; ks < 4; ++ks) {
      short8 bf[4];
#pragma unroll
      for (int n = 0; n < 4; ++n) {
        const int row = n * 16 + lr;
        bf[n] = *(const short8*)((const char*)Kt + row * 256 +
                 (((ks * 32 + lq * 8) * 2) ^ ((row & 7) << 4)));
      }
#pragma unroll
      for (int m = 0; m < 2; ++m)
#pragma unroll
        for (int n = 0; n < 4; ++n)
          sacc[m][n] = __builtin_amdgcn_mfma_f32_16x16x32_bf16(aq[m][ks], bf[n], sacc[m][n], 0, 0, 0);
    }

#pragma unroll
    for (int m = 0; m < 2; ++m)
#pragma unroll
    for (int rr = 0; rr < 4; ++rr) {
      const int prow = m * 16 + lq * 4 + rr;
      const int row_g = q0 + wrow0 + prow;
      float s[4];
      float tm = -1e30f;
#pragma unroll
      for (int n = 0; n < 4; ++n) {
        float v = sacc[m][n][rr] * SCALE;
        if (kv0 + n * 16 + lr > row_g) v = -1e30f;
        s[n] = v; tm = fmaxf(tm, v);
      }
      tm = fmaxf(tm, __shfl_xor(tm, 1));
      tm = fmaxf(tm, __shfl_xor(tm, 2));
      tm = fmaxf(tm, __shfl_xor(tm, 4));
      tm = fmaxf(tm, __shfl_xor(tm, 8));
      const float mo = mrow[m][rr];
      const float mn = fmaxf(mo, tm);
      const float scl = __expf(mo - mn);
      float ls = 0.f;
#pragma unroll
      for (int n = 0; n < 4; ++n) {
        const float p_ = __expf(s[n] - mn);
        ls += p_;
        const int col = n * 16 + lr;
        *(bf16*)((char*)Pt[wv] + prow * 128 + ((col * 2) ^ ((prow & 7) << 4))) =
            __float2bfloat16(p_);
      }
      ls += __shfl_xor(ls, 1); ls += __shfl_xor(ls, 2);
      ls += __shfl_xor(ls, 4); ls += __shfl_xor(ls, 8);
      lrow[m][rr] = lrow[m][rr] * scl + ls;
      mrow[m][rr] = mn;
#pragma unroll
      for (int n2 = 0; n2 < 8; ++n2) oacc[m][n2][rr] *= scl;
    }

#pragma unroll
    for (int ks = 0; ks < 2; ++ks) {
      short8 pa[2], vb[8];
#pragma unroll
      for (int m = 0; m < 2; ++m) {
        const int row = m * 16 + lr;
        pa[m] = *(const short8*)((const char*)Pt[wv] + row * 128 +
                 (((ks * 32 + lq * 8) * 2) ^ ((row & 7) << 4)));
      }
#pragma unroll
      for (int n2 = 0; n2 < 8; ++n2) {
        const int row = n2 * 16 + lr;
        vb[n2] = *(const short8*)((const char*)Vt + row * 128 +
                  (((ks * 32 + lq * 8) * 2) ^ ((row & 7) << 4)));
      }
#pragma unroll
      for (int m = 0; m < 2; ++m)
#pragma unroll
        for (int n2 = 0; n2 < 8; ++n2)
          oacc[m][n2] = __builtin_amdgcn_mfma_f32_16x16x32_bf16(pa[m], vb[n2], oacc[m][n2], 0, 0, 0);
    }
  }

#pragma unroll
  for (int m = 0; m < 2; ++m)
#pragma unroll
  for (int rr = 0; rr < 4; ++rr) {
    const int row_l = wrow0 + m * 16 + lq * 4 + rr;
    const float inv = 1.f / lrow[m][rr];
    bf16* orow = Hnb + ((long)(bq * S + q0 + row_l)) * D + hq * 128;
#pragma unroll
    for (int n2 = 0; n2 < 8; ++n2)
      orow[n2 * 16 + lr] = __float2bfloat16(oacc[m][n2][rr] * inv);
  }
}

// ---------------------------------------------------------------------------
// fp32 GEMM (only used for plga). MODE 0: C=A@B.
// ---------------------------------------------------------------------------
template<int MODE, int ACT>
__global__ __launch_bounds__(256) void gemm64(
    const float* __restrict__ A, const float* __restrict__ Bm,
    const float* __restrict__ bias, float* __restrict__ C,
    int M, int N, int K, int lda, int ldb,
    long sA, long sB, long sC, long sBias, float scale)
{
  A  += (long)blockIdx.z * sA;
  Bm += (long)blockIdx.z * sB;
  C  += (long)blockIdx.z * sC;
  if (bias) bias += (long)blockIdx.z * sBias;

  __shared__ float As[KT][TS + 4];
  __shared__ float Bs[KT][TS + 4];

  const int t = threadIdx.x;
  const int m0 = blockIdx.x * TS, n0 = blockIdx.y * TS;
  const int tm = (t & 15) * 4;
  const int tn = (t >> 4) * 4;

  float acc[4][4] = {};

  for (int k0 = 0; k0 < K; k0 += KT) {
    if (MODE == 2) {
      const int kk = t >> 6, mm = t & 63;
#pragma unroll
      for (int p = 0; p < 4; ++p)
        As[kk + p * 4][mm] = A[(long)(k0 + kk + p * 4) * lda + m0 + mm];
    } else {
      const int kk = t & 15, mm = t >> 4;
#pragma unroll
      for (int p = 0; p < 4; ++p)
        As[kk][mm + p * 16] = A[(long)(m0 + mm + p * 16) * lda + k0 + kk];
    }
    if (MODE == 1) {
      const int kk = t & 15, nn = t >> 4;
#pragma unroll
      for (int p = 0; p < 4; ++p)
        Bs[kk][nn + p * 16] = Bm[(long)(n0 + nn + p * 16) * ldb + k0 + kk];
    } else {
      const int kk = t >> 6, nn = t & 63;
#pragma unroll
      for (int p = 0; p < 4; ++p)
        Bs[kk + p * 4][nn] = Bm[(long)(k0 + kk + p * 4) * ldb + n0 + nn];
    }
    __syncthreads();

#pragma unroll
    for (int kk = 0; kk < KT; ++kk) {
      float4 av = *(const float4*)&As[kk][tm];
      float4 bv = *(const float4*)&Bs[kk][tn];
      float a[4] = {av.x, av.y, av.z, av.w};
      float b[4] = {bv.x, bv.y, bv.z, bv.w};
#pragma unroll
      for (int i = 0; i < 4; ++i)
#pragma unroll
        for (int j = 0; j < 4; ++j)
          acc[i][j] += a[i] * b[j];
    }
    __syncthreads();
  }

#pragma unroll
  for (int i = 0; i < 4; ++i) {
    const int m = m0 + tm + i;
#pragma unroll
    for (int j = 0; j < 4; ++j) {
      const int n = n0 + tn + j;
      float c = acc[i][j] * scale;
      if (bias) c += bias[n];
      if (ACT == 1) c = c / (1.f + __expf(-c));
      C[(long)m * N + n] = c;
    }
  }
}

// ---------------------------------------------------------------------------
// MFMA residual SwiGLU stack. Grid = 32 bh * 8 rowblocks = 256 wgs,
// 512 threads (8 waves -> 2 waves/SIMD). Each wg owns 16 rows of one (b,h)
// 128x128 A. A & g live in XOR-swizzled bf16 LDS; residual in f32 LDS.
// Weights are bf16, read directly from global as MFMA B-fragments
// (w1[o][j], w3[p][o] are already [N][K] — no transpose needed); the
// (16 rows x 64B) fragment pattern is exactly L2-line efficient.
// Per dense layer/wave: x1,x2 = 16 MFMA, A' = 8 MFMA.
// ---------------------------------------------------------------------------
__global__ __launch_bounds__(512, 1) void res_stack_mfma(
    float* __restrict__ Abuf,
    const bf16* __restrict__ w1b, const float* __restrict__ b1,
    const bf16* __restrict__ w2b, const float* __restrict__ b2,
    const bf16* __restrict__ w3b, const float* __restrict__ b3,
    const float* __restrict__ lng, const float* __restrict__ lnb)
{
  const int bh = blockIdx.x >> 3;
  const int r0 = (blockIdx.x & 7) * 16;
  float* Ag = Abuf + ((long)bh << 14) + (long)r0 * 128;

  __shared__ short As[16 * 128] __attribute__((aligned(16)));  // bf16, swizzled
  __shared__ short Gs[16 * 256] __attribute__((aligned(16)));  // bf16, swizzled
  __shared__ float Rf[16][128];

  const int t = threadIdx.x;
  const int wv = t >> 6, l = t & 63;
  const int lr = l & 15, lq = l >> 4;

  // swizzled byte offsets: row-stride 256B (As) / 512B (Gs); XOR bits 4-6.
  #define AS_OFF(row, colb) ((row) * 256 + ((colb) ^ (((row) & 7) << 4)))
  #define GS_OFF(row, colb) ((row) * 512 + ((colb) ^ (((row) & 7) << 4)))

  // initial: Ag f32 -> As bf16 (swizzled)
  for (int x = t; x < 16 * 128; x += 512) {
    const int row = x >> 7, col = x & 127;
    *(bf16*)((char*)As + AS_OFF(row, col * 2)) =
        __float2bfloat16(Ag[(long)row * 128 + col]);
  }
  __syncthreads();

  for (int lyr = 0; lyr < NRES; ++lyr) {
    // residual snapshot (f32)
    for (int x = t; x < 16 * 128; x += 512) {
      const int row = x >> 7, col = x & 127;
      Rf[row][col] = __bfloat162float(*(const bf16*)((const char*)As + AS_OFF(row, col * 2)));
    }

    for (int nd = 0; nd < NDENSE; ++nd) {
      const long wo = (long)(lyr * NDENSE + nd);
      const bf16* W1 = w1b + wo * A_DFF * DHd;   // [256][128]
      const bf16* W2 = w2b + wo * A_DFF * DHd;
      const bf16* W3 = w3b + wo * DHd * A_DFF;   // [128][256]

      // ---- step 1: x1,x2 for cols wv*32 + n*16 + lr (wave owns 32 of 256)
      f32x4 a1[2] = {}, a2[2] = {};
#pragma unroll
      for (int ks = 0; ks < 4; ++ks) {
        const short8 av = *(const short8*)((const char*)As + AS_OFF(lr, (ks * 32 + lq * 8) * 2));
#pragma unroll
        for (int n = 0; n < 2; ++n) {
          const int brow = wv * 32 + n * 16 + lr;
          const short8 b1f = *(const short8*)&W1[(long)brow * 128 + ks * 32 + lq * 8];
          const short8 b2f = *(const short8*)&W2[(long)brow * 128 + ks * 32 + lq * 8];
          a1[n] = __builtin_amdgcn_mfma_f32_16x16x32_bf16(av, b1f, a1[n], 0, 0, 0);
          a2[n] = __builtin_amdgcn_mfma_f32_16x16x32_bf16(av, b2f, a2[n], 0, 0, 0);
        }
      }
      // ---- step 2: bias + SiLU + gate -> Gs (bf16, swizzled)
#pragma unroll
      for (int n = 0; n < 2; ++n) {
        const int col = wv * 32 + n * 16 + lr;
        const float bb1 = b1[wo * A_DFF + col];
        const float bb2 = b2[wo * A_DFF + col];
#pragma unroll
        for (int rr = 0; rr < 4; ++rr) {
          const int row = lq * 4 + rr;
          float x1 = a1[n][rr] + bb1;
          x1 = x1 / (1.f + __expf(-x1));
          const float gv = x1 * (a2[n][rr] + bb2);
          *(bf16*)((char*)Gs + GS_OFF(row, col * 2)) = __float2bfloat16(gv);
        }
      }
      __syncthreads();

      // ---- step 3: A'[.,wv*16+lr] = g @ w3^T, K=256
      f32x4 a3 = {};
#pragma unroll
      for (int ks = 0; ks < 8; ++ks) {
        const short8 gf = *(const short8*)((const char*)Gs + GS_OFF(lr, (ks * 32 + lq * 8) * 2));
        const int brow = wv * 16 + lr;
        const short8 b3f = *(const short8*)&W3[(long)brow * 256 + ks * 32 + lq * 8];
        a3 = __builtin_amdgcn_mfma_f32_16x16x32_bf16(gf, b3f, a3, 0, 0, 0);
      }
      // ---- step 4: bias, write A' -> As (all waves passed step-2 barrier)
      {
        const int col = wv * 16 + lr;
        const float bb3 = b3[wo * DHd + col];
#pragma unroll
        for (int rr = 0; rr < 4; ++rr) {
          const int row = lq * 4 + rr;
          *(bf16*)((char*)As + AS_OFF(row, col * 2)) = __float2bfloat16(a3[rr] + bb3);
        }
      }
      __syncthreads();
    }

    // ---- LN(A' + Res): wave wv handles rows wv*2..+2, lane covers 2 cols
#pragma unroll
    for (int i = wv * 2; i < wv * 2 + 2; ++i) {
      const float v0 = __bfloat162float(*(const bf16*)((const char*)As + AS_OFF(i, l * 2))) + Rf[i][l];
      const float v1 = __bfloat162float(*(const bf16*)((const char*)As + AS_OFF(i, (l + 64) * 2))) + Rf[i][l + 64];
      float s = v0 + v1;
#pragma unroll
      for (int o = 32; o > 0; o >>= 1) s += __shfl_down(s, o);
      const float mu = __shfl(s, 0) * (1.f / 128.f);
      const float d0 = v0 - mu, d1 = v1 - mu;
      float vs = d0 * d0 + d1 * d1;
#pragma unroll
      for (int o = 32; o > 0; o >>= 1) vs += __shfl_down(vs, o);
      const float rstd = rsqrtf(__shfl(vs, 0) * (1.f / 128.f) + EPSV);
      const float o0 = d0 * rstd * lng[lyr * 128 + l] + lnb[lyr * 128 + l];
      const float o1 = d1 * rstd * lng[lyr * 128 + l + 64] + lnb[lyr * 128 + l + 64];
      if (lyr == NRES - 1) {
        Ag[(long)i * 128 + l]      = o0;
        Ag[(long)i * 128 + l + 64] = o1;
      } else {
        *(bf16*)((char*)As + AS_OFF(i, l * 2))        = __float2bfloat16(o0);
        *(bf16*)((char*)As + AS_OFF(i, (l + 64) * 2)) = __float2bfloat16(o1);
      }
    }
    __syncthreads();
  }
  #undef AS_OFF
  #undef GS_OFF
}

// f32 -> bf16 convert, 4 elems/thread
__global__ __launch_bounds__(256) void f2b(const float* __restrict__ in,
                                           bf16* __restrict__ out)
{
  const long i = (long)blockIdx.x * 256 + threadIdx.x;
  const float4 v = ((const float4*)in)[i];
  bf16* o = out + i * 4;
  o[0] = __float2bfloat16(v.x); o[1] = __float2bfloat16(v.y);
  o[2] = __float2bfloat16(v.z); o[3] = __float2bfloat16(v.w);
}

// LayerNorm rows of 128 (for ln1), in-place safe.
__global__ __launch_bounds__(64) void ln_row(
    const float* __restrict__ in, const float* __restrict__ g,
    const float* __restrict__ b, float* __restrict__ out)
{
  const long r = blockIdx.x;
  const int t = threadIdx.x;
  float v0 = in[r * 128 + t], v1 = in[r * 128 + t + 64];
  float s = v0 + v1;
#pragma unroll
  for (int o = 32; o > 0; o >>= 1) s += __shfl_down(s, o);
  const float mu = __shfl(s, 0) * (1.f / 128.f);
  const float d0 = v0 - mu, d1 = v1 - mu;
  float vs = d0 * d0 + d1 * d1;
#pragma unroll
  for (int o = 32; o > 0; o >>= 1) vs += __shfl_down(vs, o);
  const float rstd = rsqrtf(__shfl(vs, 0) * (1.f / 128.f) + EPSV);
  out[r * 128 + t]      = d0 * rstd * g[t] + b[t];
  out[r * 128 + t + 64] = d1 * rstd * g[t + 64] + b[t + 64];
}

// [B,S,H,DH] f32 -> [B,H,S,DH] bf16 with RoPE.
__global__ __launch_bounds__(256) void rope_tr2(const float* __restrict__ in,
                                                bf16* __restrict__ outb)
{
  const long idx = (long)blockIdx.x * 256 + threadIdx.x;
  const int p = idx & 63;
  const int h = (idx >> 6) & (H - 1);
  const int s = (idx >> 10) & (S - 1);
  const int b = (int)(idx >> 21);
  const float theta = powf(10000.f, -(float)p * (1.f / 64.f));
  float sn, cs;
  sincosf((float)s * theta, &sn, &cs);
  const long src = (((long)(b * S + s) * H + h) << 7) + 2 * p;
  const float x1 = in[src], x2 = in[src + 1];
  const long dst = (((long)(b * H + h) * S + s) << 7) + 2 * p;
  outb[dst]     = __float2bfloat16(x1 * cs - x2 * sn);
  outb[dst + 1] = __float2bfloat16(x2 * cs + x1 * sn);
}

// bf16 tiled transpose: [BH][S][128] -> [BH][128][S]
__global__ __launch_bounds__(256) void tr_qT(const bf16* __restrict__ in,
                                             bf16* __restrict__ outT)
{
  __shared__ unsigned short tile[64][68];
  const int t = threadIdx.x;
  const int s0 = blockIdx.x * 64, d0 = blockIdx.y * 64;
  const long bh = blockIdx.z;
  const unsigned short* ip = (const unsigned short*)in + (bh * S + s0) * 128 + d0;
  unsigned short* op = (unsigned short*)outT + (bh * 128 + d0) * S + s0;
  const int r = t >> 4, c = (t & 15) * 4;
#pragma unroll
  for (int p = 0; p < 4; ++p) {
    const ushort4 v = *(const ushort4*)&ip[(long)(r + p * 16) * 128 + c];
    tile[r + p * 16][c]     = v.x;
    tile[r + p * 16][c + 1] = v.y;
    tile[r + p * 16][c + 2] = v.z;
    tile[r + p * 16][c + 3] = v.w;
  }
  __syncthreads();
#pragma unroll
  for (int p = 0; p < 4; ++p) {
    ushort4 w;
    w.x = tile[c][r + p * 16];
    w.y = tile[c + 1][r + p * 16];
    w.z = tile[c + 2][r + p * 16];
    w.w = tile[c + 3][r + p * 16];
    *(ushort4*)&op[(long)(r + p * 16) * S + c] = w;
  }
}

// [B,S,H,DH] f32 -> vT bf16 [B,H,DH,S]
__global__ __launch_bounds__(256) void tr_v_b(const float* __restrict__ in,
                                              bf16* __restrict__ out)
{
  const long idx = (long)blockIdx.x * 256 + threadIdx.x;
  const int s = idx & (S - 1);
  const int dh = (idx >> 11) & 127;
  const int h = (idx >> 18) & (H - 1);
  const int b = (int)(idx >> 22);
  out[idx] = __float2bfloat16(in[(((long)(b * S + s) * H + h) << 7) + dh]);
}

// G = sign/pow(leaky_relu(A_LM)); f32 [bh,d,f] -> bf16 G^T [bh,f,d]
__global__ __launch_bounds__(256) void plga_g_t(const float* __restrict__ a,
                                                const float* __restrict__ pw,
                                                bf16* __restrict__ gt)
{
  const long idx = (long)blockIdx.x * 256 + threadIdx.x;
  const int f = idx & 127;
  const int dd = (idx >> 7) & 127;
  const int bh = (int)(idx >> 14);
  const int h = bh & (H - 1);
  float x = a[idx];
  x = x > 0.f ? x : NEG_SLOPE * x;
  const float gq = powf(fabsf(x) + EPSV, pw[h]);
  const float gv = x > 0.f ? gq : (x < 0.f ? -gq : 0.f);
  gt[((long)bh << 14) + f * 128 + dd] = __float2bfloat16(gv);
}

}  // namespace

extern "C" void kernel_launch(void* const* d_in, const int* in_sizes, int n_in,
                              void* d_out, int out_size, void* d_ws, size_t ws_size,
                              hipStream_t stream)
{
  const float* q_in    = (const float*)d_in[0];
  const float* k_in    = (const float*)d_in[1];
  const float* v_in    = (const float*)d_in[2];
  const float* wq_w    = (const float*)d_in[4];
  const float* wq_b    = (const float*)d_in[5];
  const float* wk_w    = (const float*)d_in[6];
  const float* wk_b    = (const float*)d_in[7];
  const float* wv_w    = (const float*)d_in[8];
  const float* wv_b    = (const float*)d_in[9];
  const float* dense_w = (const float*)d_in[10];
  const float* dense_b = (const float*)d_in[11];
  const float* ln1_g   = (const float*)d_in[12];
  const float* ln1_b   = (const float*)d_in[13];
  const float* res_w1  = (const float*)d_in[14];
  const float* res_b1  = (const float*)d_in[15];
  const float* res_w2  = (const float*)d_in[16];
  const float* res_b2  = (const float*)d_in[17];
  const float* res_w3  = (const float*)d_in[18];
  const float* res_b3  = (const float*)d_in[19];
  const float* res_lng = (const float*)d_in[20];
  const float* res_lnb = (const float*)d_in[21];
  const float* plga_W  = (const float*)d_in[22];
  const float* plga_b  = (const float*)d_in[23];
  const float* plga_pw = (const float*)d_in[24];
  float* out = (float*)d_out;

  const long NBS = (long)B * S * D;            // 8388608
  const long NA  = (long)B * H * DHd * DHd;    // 524288
  const long DDw = (long)D * D;                // 4194304
  const long NW  = (long)NRES * NDENSE * A_DFF * DHd;  // 524288

  float* ws = (float*)d_ws;
  float* qp = ws;               // q proj f32
  float* kp = ws + NBS;         // k proj f32; later Hnb bf16
  float* vp = ws + 2 * NBS;     // v proj f32; later Abuf/Gb f32
  float* qhslot = ws + 3 * NBS; // qTb bf16 (1st half), GTb bf16 (2nd half)
  float* Abuf = vp;
  float* Gb   = vp + NA;

  bf16* bbase = (bf16*)(ws + 4 * NBS);
  bf16* qb  = bbase;            // q_in bf16; later qhb
  bf16* kb  = bbase + NBS;      // k_in bf16; later khb
  bf16* vb  = bbase + 2 * NBS;  // v_in bf16; later vT
  bf16* wqb = bbase + 3 * NBS;  // later qgb
  bf16* wkb = wqb + DDw;
  bf16* wvb = wqb + 2 * DDw;    // later wdb
  bf16* qhb = qb;
  bf16* khb = kb;
  bf16* vT  = vb;
  bf16* qgb = wqb;
  bf16* wdb = wvb;
  bf16* qTb = (bf16*)qhslot;
  bf16* GTb = (bf16*)qhslot + NBS;
  bf16* Hnb = (bf16*)kp;
  bf16* w1bb = bbase + 3 * NBS + 3 * DDw;   // res weights bf16
  bf16* w2bb = w1bb + NW;
  bf16* w3bb = w2bb + NW;

  // ---- convert inputs + weights to bf16 (res weights need no transpose:
  //      w1[o][j], w3[p][o] are already [N][K] for the MFMA B operand)
  f2b<<<(int)(NBS / 1024), 256, 0, stream>>>(q_in, qb);
  f2b<<<(int)(NBS / 1024), 256, 0, stream>>>(k_in, kb);
  f2b<<<(int)(NBS / 1024), 256, 0, stream>>>(v_in, vb);
  f2b<<<(int)(DDw / 1024), 256, 0, stream>>>(wq_w, wqb);
  f2b<<<(int)(DDw / 1024), 256, 0, stream>>>(wk_w, wkb);
  f2b<<<(int)(DDw / 1024), 256, 0, stream>>>(wv_w, wvb);
  f2b<<<(int)(NW / 1024), 256, 0, stream>>>(res_w1, w1bb);
  f2b<<<(int)(NW / 1024), 256, 0, stream>>>(res_w2, w2bb);
  f2b<<<(int)(NW / 1024), 256, 0, stream>>>(res_w3, w3bb);

  // ---- QKV projections (bf16 MFMA)
  gemm_bt_mfma<false, true><<<dim3(32, 16, 1), 256, 0, stream>>>(
      qb, wqb, wq_b, qp, D, D, D, D, 0, 0, 0, 1.f);
  gemm_bt_mfma<false, true><<<dim3(32, 16, 1), 256, 0, stream>>>(
      kb, wkb, wk_b, kp, D, D, D, D, 0, 0, 0, 1.f);
  gemm_bt_mfma<false, true><<<dim3(32, 16, 1), 256, 0, stream>>>(
      vb, wvb, wv_b, vp, D, D, D, D, 0, 0, 0, 1.f);

  f2b<<<(int)(DDw / 1024), 256, 0, stream>>>(dense_w, wdb);

  // ---- RoPE + head transposes
  rope_tr2<<<16384, 256, 0, stream>>>(qp, qhb);
  rope_tr2<<<16384, 256, 0, stream>>>(kp, khb);
  tr_v_b<<<32768, 256, 0, stream>>>(vp, vT);
  tr_qT<<<dim3(32, 2, 32), 256, 0, stream>>>(qhb, qTb);

  // ---- metric A = q^T q per (b,h): split-K MFMA + f32 atomics
  hipMemsetAsync(Abuf, 0, NA * sizeof(float), stream);
  qtq_splitk<<<dim3(KSPLIT, 1, 32), 256, 0, stream>>>(qTb, Abuf);
  ln_row<<<B * H * DHd, 64, 0, stream>>>(Abuf, ln1_g, ln1_b, Abuf);

  // ---- fused residual SwiGLU stack (bf16 MFMA, one dispatch)
  res_stack_mfma<<<256, 512, 0, stream>>>(Abuf, w1bb, res_b1, w2bb, res_b2,
                                          w3bb, res_b3, res_lng, res_lnb);

  // ---- plga (fp32), then G^T bf16
  for (int b2 = 0; b2 < B; ++b2)
    gemm64<0, 0><<<dim3(2, 2, 16), 256, 0, stream>>>(plga_W,
        Abuf + (long)b2 * H * DHd * DHd, plga_b, Gb + (long)b2 * H * DHd * DHd,
        DHd, DHd, DHd, DHd, DHd,
        (long)DHd * DHd, (long)DHd * DHd, (long)DHd * DHd, DHd, 1.f);
  plga_g_t<<<(int)(NA / 256), 256, 0, stream>>>(Gb, plga_pw, GTb);

  // ---- qg = q @ G per (b,h)
  gemm_bt_mfma<true, false><<<dim3(16, 1, 32), 256, 0, stream>>>(
      qhb, GTb, nullptr, qgb, DHd, DHd, DHd, DHd,
      (long)S * DHd, (long)DHd * DHd, (long)S * DHd, 1.f);

  // ---- fused causal flash attention (one dispatch)
  flash_attn<<<dim3(16, 1, 32), 256, 0, stream>>>(qgb, khb, vT, Hnb);

  // ---- final dense (f32 out)
  gemm_bt_mfma<false, true><<<dim3(32, 16, 1), 256, 0, stream>>>(
      Hnb, wdb, dense_b, out, D, D, D, D, 0, 0, 0, 1.f);
}